// Round 4
// baseline (307.359 us; speedup 1.0000x reference)
//
#include <hip/hip_runtime.h>
#include <math.h>

#define H_IN  1024
#define W_IN  1024
#define HW_IN (H_IN * W_IN)
#define H_OUT 768
#define W_OUT 768
#define HW_OUT (H_OUT * W_OUT)

// LDS staging of the packed plane: 28x28 pixels x 6 floats
#define SROWS 28
#define SPX   28
#define RS    (SPX * 6)        // 168 floats; %32 banks = +8 stagger per row
#define NELEM4 (SROWS * (RS / 4))   // 1176 float4 per tile

struct KC {
    float sig1, inv, slope, two_over_c, half_c, quarter_c, half_over_sig1;
    float a2, a0, m_in_root;
};

__device__ __forceinline__ float inv_sigmoid(float q, const KC k) {
    if (q <= 0.f) return q * k.inv;
    if (q >= 1.f) return q * k.inv + (1.f - k.inv);
    float ssq = 2.f * k.sig1 * q - k.sig1;
    ssq = fminf(fmaxf(ssq, -0.999999f), 0.999999f);
    return k.two_over_c * atanhf(ssq) + 0.5f;
}

__device__ __forceinline__ float ext_sigmoid(float q, const KC k) {
    if (q <= 0.f) return k.slope * q;
    if (q >= 1.f) return k.slope * q + (1.f - k.slope);
    return k.half_over_sig1 * tanhf(k.half_c * q - k.quarter_c) + 0.5f;
}

__device__ __forceinline__ float mitchell(float xv) {
    float ax = fabsf(xv);
    if (ax >= 2.f) return 0.f;
    float ax2 = ax * ax, ax3 = ax2 * ax;
    if (ax < 1.f) return 7.f / 6.f * ax3 - 2.f * ax2 + 8.f / 9.f;
    return -7.f / 18.f * ax3 + 2.f * ax2 - 10.f / 3.f * ax + 16.f / 9.f;
}

__device__ __forceinline__ float robidoux(float r2, const KC k) {
    if (r2 >= 4.f) return 0.f;
    float r = sqrtf(r2 + 1e-8f);
    if (r2 < 1.f) return r2 * (-3.f * r + k.a2) + k.a0;
    float t = r - 2.f;
    return (r + k.m_in_root) * t * t;
}

// Pack [p0,s0,p1,s1,p2,s2] per pixel (linear read, linear write).
__global__ __launch_bounds__(256)
void pack_kernel(const float* __restrict__ img, float* __restrict__ packed, KC k) {
    int i = blockIdx.x * 256 + threadIdx.x;
    if (i >= HW_IN / 2) return;
    int x2 = i * 2;
    float2 c0 = *(const float2*)&img[x2];
    float2 c1 = *(const float2*)&img[HW_IN + x2];
    float2 c2 = *(const float2*)&img[2 * HW_IN + x2];
    float4 o0 = make_float4(c0.x, inv_sigmoid(c0.x, k), c1.x, inv_sigmoid(c1.x, k));
    float4 o1 = make_float4(c2.x, inv_sigmoid(c2.x, k), c0.y, inv_sigmoid(c0.y, k));
    float4 o2 = make_float4(c1.y, inv_sigmoid(c1.y, k), c2.y, inv_sigmoid(c2.y, k));
    float4* o = (float4*)packed + (size_t)3 * i;
    o[0] = o0; o[1] = o1; o[2] = o2;
}

__global__ __launch_bounds__(256, 4)   // cap VGPR at 128 -> 4 wg/CU
void lohalo_lds(const float* __restrict__ packed, const float* __restrict__ grid,
                float* __restrict__ out, KC k) {
    __shared__ float sm[SROWS * RS];   // 18816 B
    __shared__ int sred[16];

    // XCD-aware swizzle: 2304 blocks, 288 contiguous per XCD (6 block-rows)
    const int bid = blockIdx.x;
    const int swz = (bid & 7) * 288 + (bid >> 3);
    const int bx = swz % 48, by = swz / 48;

    const int tid = threadIdx.x;
    const int lx = tid & 15, ly = tid >> 4;
    const int x = bx * 16 + lx;
    const int y = by * 16 + ly;
    const int pix = y * W_OUT + x;

    // ---- Jacobian ----
    const float2* G = (const float2*)grid;
    float2 gc  = G[pix];
    float2 gxm = G[y * W_OUT + max(x - 1, 0)];
    float2 gxp = G[y * W_OUT + min(x + 1, W_OUT - 1)];
    float2 gym = G[max(y - 1, 0) * W_OUT + x];
    float2 gyp = G[min(y + 1, H_OUT - 1) * W_OUT + x];
    float J00 = (gxp.x - gxm.x) * 0.5f, J10 = (gxp.y - gxm.y) * 0.5f;
    float J01 = (gyp.x - gym.x) * 0.5f, J11 = (gyp.y - gym.y) * 0.5f;
    float det = J00 * J11 - J01 * J10 + 1e-8f;
    float a  = J11 / det, b = -J01 / det;
    float cI = -J10 / det, d = J00 / det;
    float n11 = a * a + b * b, n12 = a * cI + b * d, n22 = cI * cI + d * d;
    float frob = n11 + n22;
    float disc = frob * frob - 4.f / (det * det);
    float sdisc = sqrtf(fmaxf(disc, 0.f));
    float twice = frob + sdisc;
    float s1s1 = 0.5f * twice, s2s2 = 0.5f * (frob - sdisc);
    float major = sqrtf(fmaxf(s1s1, 1.f));
    float minr  = sqrtf(fmaxf(s2s2, 1.f));
    float diff1 = s1s1 - n11, diff2 = s1s1 - n22;
    bool  cnd  = diff1 * diff1 >= diff2 * diff2;
    float tu11 = cnd ? n12 : diff2;
    float tu21 = cnd ? diff1 : n12;
    float nrm = sqrtf(tu11 * tu11 + tu21 * tu21);
    float u11 = nrm > 0.f ? tu11 / nrm : 1.f;
    float u21 = nrm > 0.f ? tu21 / nrm : 0.f;
    float cMx = u11 / major, cMy = u21 / major;
    float cmx = -u21 / minr, cmy = u11 / minr;
    float theta = 1.f / (major * minr);
    bool need_ewa = twice > 2.f;

    float fix = floorf(gc.x), fiy = floorf(gc.y);
    int ix = (int)fix, iy = (int)fiy;
    float fx = gc.x - (fix + 0.5f);
    float fy = gc.y - (fiy + 0.5f);

    // ---- block bbox ----
    int mnx = ix, mxx = ix, mny = iy, mxy = iy;
#pragma unroll
    for (int m = 1; m < 64; m <<= 1) {
        mnx = min(mnx, __shfl_xor(mnx, m));
        mxx = max(mxx, __shfl_xor(mxx, m));
        mny = min(mny, __shfl_xor(mny, m));
        mxy = max(mxy, __shfl_xor(mxy, m));
    }
    const int wid = tid >> 6;
    if ((tid & 63) == 0) {
        sred[wid * 4 + 0] = mnx;
        sred[wid * 4 + 1] = mxx;
        sred[wid * 4 + 2] = mny;
        sred[wid * 4 + 3] = mxy;
    }
    __syncthreads();
    mnx = min(min(sred[0], sred[4]),  min(sred[8],  sred[12]));
    mxx = max(max(sred[1], sred[5]),  max(sred[9],  sred[13]));
    mny = min(min(sred[2], sred[6]),  min(sred[10], sred[14]));
    mxy = max(max(sred[3], sred[7]),  max(sred[11], sred[15]));

    const int x0 = (mnx - 2) & ~1;     // float4-aligned in packed (even pixel)
    const int y0 = mny - 2;
    const bool fits = (mxx + 3 - x0 < SPX) && (mxy + 3 - y0 < SROWS);

    // ---- weights ----
    float my6[6], qya[6], qyb[6], mx6[6], qxa[6], qxb[6];
    int cxi[6], cyi[6];
#pragma unroll
    for (int t = 0; t < 6; t++) {
        float relx = fx - (float)(t - 2);
        float rely = fy - (float)(t - 2);
        mx6[t] = mitchell(relx);
        my6[t] = mitchell(rely);
        qxa[t] = relx * cMx; qxb[t] = relx * cmx;
        qya[t] = rely * cMy; qyb[t] = rely * cmy;
        cxi[t] = min(max(ix + (t - 2), 0), W_IN - 1);
        cyi[t] = min(max(iy + (t - 2), 0), H_IN - 1);
    }

    float ms0 = 0.f, ms1 = 0.f, ms2 = 0.f;
    float es0 = 0.f, es1 = 0.f, es2 = 0.f, tw = 0.f;

    if (fits) {
        // ---- stage tile into LDS ----
        if (x0 >= 0 && x0 + SPX <= W_IN) {
            // vector path: 1176 float4, ~5 per thread, coalesced
            for (int j = tid; j < NELEM4; j += 256) {
                int r = j / (RS / 4);
                int q = j - r * (RS / 4);
                int gr = min(max(y0 + r, 0), H_IN - 1);
                const float4* src = (const float4*)(packed + ((size_t)gr * W_IN + x0) * 6) + q;
                *(float4*)&sm[r * RS + q * 4] = *src;
            }
        } else {
            // x-border: per-pixel with clamped column
            for (int j = tid; j < SROWS * SPX; j += 256) {
                int r = j / SPX;
                int c = j - r * SPX;
                int gr = min(max(y0 + r, 0), H_IN - 1);
                int gcc = min(max(x0 + c, 0), W_IN - 1);
                const float2* src = (const float2*)(packed + ((size_t)gr * W_IN + gcc) * 6);
                float2 a0 = src[0], a1 = src[1], a2 = src[2];
                int o = r * RS + c * 6;
                *(float2*)&sm[o]     = a0;
                *(float2*)&sm[o + 2] = a1;
                *(float2*)&sm[o + 4] = a2;
            }
        }
        __syncthreads();

        int lxo[6], lyo[6];
#pragma unroll
        for (int t = 0; t < 6; t++) {
            lxo[t] = (cxi[t] - x0) * 6;
            lyo[t] = (cyi[t] - y0) * RS;
        }

#pragma unroll
        for (int ty = 0; ty < 6; ty++) {
            const int rb = lyo[ty];
            const float wmy = my6[ty];
            const float qy1 = qya[ty], qy2 = qyb[ty];
#pragma unroll
            for (int tx = 0; tx < 6; tx++) {
                const int o = rb + lxo[tx];
                float2 f0 = *(float2*)&sm[o];
                float2 f1 = *(float2*)&sm[o + 2];
                float2 f2 = *(float2*)&sm[o + 4];
                float wm = mx6[tx] * wmy;
                ms0 = fmaf(f0.y, wm, ms0);
                ms1 = fmaf(f1.y, wm, ms1);
                ms2 = fmaf(f2.y, wm, ms2);
                float q1 = qxa[tx] + qy1;
                float q2 = qxb[tx] + qy2;
                float r2 = q1 * q1 + q2 * q2;
                float we = robidoux(r2, k);
                tw += we;
                es0 = fmaf(f0.x, we, es0);
                es1 = fmaf(f1.x, we, es1);
                es2 = fmaf(f2.x, we, es2);
            }
        }
    } else {
        // safety net (bbox larger than tile): direct gather from packed
#pragma unroll
        for (int ty = 0; ty < 6; ty++) {
            const int rb = cyi[ty] * W_IN;
            const float wmy = my6[ty];
            const float qy1 = qya[ty], qy2 = qyb[ty];
#pragma unroll
            for (int tx = 0; tx < 6; tx++) {
                const float* pp = packed + (size_t)(rb + cxi[tx]) * 6;
                float2 f0 = *(const float2*)(pp);
                float2 f1 = *(const float2*)(pp + 2);
                float2 f2 = *(const float2*)(pp + 4);
                float wm = mx6[tx] * wmy;
                ms0 = fmaf(f0.y, wm, ms0);
                ms1 = fmaf(f1.y, wm, ms1);
                ms2 = fmaf(f2.y, wm, ms2);
                float q1 = qxa[tx] + qy1;
                float q2 = qxb[tx] + qy2;
                float r2 = q1 * q1 + q2 * q2;
                float we = robidoux(r2, k);
                tw += we;
                es0 = fmaf(f0.x, we, es0);
                es1 = fmaf(f1.x, we, es1);
                es2 = fmaf(f2.x, we, es2);
            }
        }
    }

    tw += 1e-8f;
    float itw = 1.f / tw;
    float mv0 = ext_sigmoid(ms0, k);
    float mv1 = ext_sigmoid(ms1, k);
    float mv2 = ext_sigmoid(ms2, k);
    float om = 1.f - theta;
    out[pix]              = need_ewa ? theta * mv0 + om * (es0 * itw) : mv0;
    out[HW_OUT + pix]     = need_ewa ? theta * mv1 + om * (es1 * itw) : mv1;
    out[2 * HW_OUT + pix] = need_ewa ? theta * mv2 + om * (es2 * itw) : mv2;
}

// Fallback if ws too small: direct gather from img (unpacked).
__global__ __launch_bounds__(256)
void lohalo_fallback(const float* __restrict__ img, const float* __restrict__ grid,
                     float* __restrict__ out, KC k) {
    const int tid = threadIdx.x;
    const int lx = tid & 15, ly = tid >> 4;
    const int x = blockIdx.x * 16 + lx;
    const int y = blockIdx.y * 16 + ly;
    const int pix = y * W_OUT + x;

    const float2* G = (const float2*)grid;
    float2 gc  = G[pix];
    float2 gxm = G[y * W_OUT + max(x - 1, 0)];
    float2 gxp = G[y * W_OUT + min(x + 1, W_OUT - 1)];
    float2 gym = G[max(y - 1, 0) * W_OUT + x];
    float2 gyp = G[min(y + 1, H_OUT - 1) * W_OUT + x];
    float J00 = (gxp.x - gxm.x) * 0.5f, J10 = (gxp.y - gxm.y) * 0.5f;
    float J01 = (gyp.x - gym.x) * 0.5f, J11 = (gyp.y - gym.y) * 0.5f;
    float det = J00 * J11 - J01 * J10 + 1e-8f;
    float a  = J11 / det, b = -J01 / det;
    float cI = -J10 / det, d = J00 / det;
    float n11 = a * a + b * b, n12 = a * cI + b * d, n22 = cI * cI + d * d;
    float frob = n11 + n22;
    float disc = frob * frob - 4.f / (det * det);
    float sdisc = sqrtf(fmaxf(disc, 0.f));
    float twice = frob + sdisc;
    float s1s1 = 0.5f * twice, s2s2 = 0.5f * (frob - sdisc);
    float major = sqrtf(fmaxf(s1s1, 1.f));
    float minr  = sqrtf(fmaxf(s2s2, 1.f));
    float diff1 = s1s1 - n11, diff2 = s1s1 - n22;
    bool  cnd  = diff1 * diff1 >= diff2 * diff2;
    float tu11 = cnd ? n12 : diff2;
    float tu21 = cnd ? diff1 : n12;
    float nrm = sqrtf(tu11 * tu11 + tu21 * tu21);
    float u11 = nrm > 0.f ? tu11 / nrm : 1.f;
    float u21 = nrm > 0.f ? tu21 / nrm : 0.f;
    float cMx = u11 / major, cMy = u21 / major;
    float cmx = -u21 / minr, cmy = u11 / minr;
    float theta = 1.f / (major * minr);
    bool need_ewa = twice > 2.f;

    float fix = floorf(gc.x), fiy = floorf(gc.y);
    int ix = (int)fix, iy = (int)fiy;
    float fx = gc.x - (fix + 0.5f);
    float fy = gc.y - (fiy + 0.5f);

    float mtx[6], mty[6], qxa6[6], qxb6[6], qya6[6], qyb6[6];
    int cxi[6], cyi[6];
#pragma unroll
    for (int t = 0; t < 6; t++) {
        float relx = fx - (float)(t - 2);
        float rely = fy - (float)(t - 2);
        mtx[t] = mitchell(relx);
        mty[t] = mitchell(rely);
        qxa6[t] = relx * cMx; qxb6[t] = relx * cmx;
        qya6[t] = rely * cMy; qyb6[t] = rely * cmy;
        cxi[t] = min(max(ix + (t - 2), 0), W_IN - 1);
        cyi[t] = min(max(iy + (t - 2), 0), H_IN - 1);
    }
    float ms0 = 0.f, ms1 = 0.f, ms2 = 0.f;
    float es0 = 0.f, es1 = 0.f, es2 = 0.f, tw = 0.f;
#pragma unroll
    for (int ty = 0; ty < 6; ty++) {
        const int rb = cyi[ty] * W_IN;
        const float wmy = mty[ty];
#pragma unroll
        for (int tx = 0; tx < 6; tx++) {
            const int off = rb + cxi[tx];
            float p0 = img[off];
            float p1 = img[off + HW_IN];
            float p2 = img[off + 2 * HW_IN];
            float s0 = inv_sigmoid(p0, k);
            float s1 = inv_sigmoid(p1, k);
            float s2 = inv_sigmoid(p2, k);
            float wm = mtx[tx] * wmy;
            ms0 = fmaf(s0, wm, ms0);
            ms1 = fmaf(s1, wm, ms1);
            ms2 = fmaf(s2, wm, ms2);
            float q1 = qxa6[tx] + qya6[ty];
            float q2 = qxb6[tx] + qyb6[ty];
            float r2 = q1 * q1 + q2 * q2;
            float we = robidoux(r2, k);
            tw += we;
            es0 = fmaf(p0, we, es0);
            es1 = fmaf(p1, we, es1);
            es2 = fmaf(p2, we, es2);
        }
    }
    tw += 1e-8f;
    float itw = 1.f / tw;
    float mv0 = ext_sigmoid(ms0, k);
    float mv1 = ext_sigmoid(ms1, k);
    float mv2 = ext_sigmoid(ms2, k);
    float om = 1.f - theta;
    out[pix]              = need_ewa ? theta * mv0 + om * (es0 * itw) : mv0;
    out[HW_OUT + pix]     = need_ewa ? theta * mv1 + om * (es1 * itw) : mv1;
    out[2 * HW_OUT + pix] = need_ewa ? theta * mv2 + om * (es2 * itw) : mv2;
}

extern "C" void kernel_launch(void* const* d_in, const int* in_sizes, int n_in,
                              void* d_out, int out_size, void* d_ws, size_t ws_size,
                              hipStream_t stream) {
    const float* img  = (const float*)d_in[0];
    const float* grid = (const float*)d_in[1];
    float* out = (float*)d_out;

    KC k;
    const double cc = 3.38589;
    const double s1 = tanh(0.25 * cc);
    const double slope = (1.0 / s1 - s1) * 0.25 * cc;
    k.sig1 = (float)s1;
    k.slope = (float)slope;
    k.inv = (float)(1.0 / slope);
    k.two_over_c = (float)(2.0 / cc);
    k.half_c = (float)(0.5 * cc);
    k.quarter_c = (float)(0.25 * cc);
    k.half_over_sig1 = (float)(0.5 / s1);
    const double sq2 = sqrt(2.0);
    k.a2 = (float)((45739.0 + 7164.0 * sq2) / 10319.0);
    k.a0 = (float)((-8926.0 - 14328.0 * sq2) / 10319.0);
    k.m_in_root = (float)((-103.0 - 36.0 * sq2) / (7.0 + 72.0 * sq2));

    const size_t packed_bytes = (size_t)HW_IN * 6 * sizeof(float);   // 24 MB

    if (ws_size >= packed_bytes) {
        float* packed = (float*)d_ws;
        int npairs = HW_IN / 2;
        pack_kernel<<<(npairs + 255) / 256, 256, 0, stream>>>(img, packed, k);
        lohalo_lds<<<(W_OUT / 16) * (H_OUT / 16), 256, 0, stream>>>(packed, grid, out, k);
    } else {
        dim3 grd(W_OUT / 16, H_OUT / 16);
        lohalo_fallback<<<grd, 256, 0, stream>>>(img, grid, out, k);
    }
}

// Round 5
// 101.080 us; speedup vs baseline: 3.0407x; 3.0407x over previous
//
#include <hip/hip_runtime.h>
#include <math.h>

#define H_IN  1024
#define W_IN  1024
#define HW_IN (H_IN * W_IN)
#define H_OUT 768
#define W_OUT 768
#define HW_OUT (H_OUT * W_OUT)

// LDS tile: 28x28 pixels x 6 floats (clamped at stage time)
#define SROWS 28
#define SPX   28
#define RS    (SPX * 6)             // 168 floats/row
#define NELEM4 (SROWS * (RS / 4))   // 1176 float4

struct KC {
    float sig1, inv, slope, two_over_c, half_c, quarter_c, half_over_sig1;
    float a2, a0, m_in_root;
};

__device__ __forceinline__ float inv_sigmoid(float q, const KC k) {
    if (q <= 0.f) return q * k.inv;
    if (q >= 1.f) return q * k.inv + (1.f - k.inv);
    float ssq = 2.f * k.sig1 * q - k.sig1;
    ssq = fminf(fmaxf(ssq, -0.999999f), 0.999999f);
    return k.two_over_c * atanhf(ssq) + 0.5f;
}

__device__ __forceinline__ float ext_sigmoid(float q, const KC k) {
    if (q <= 0.f) return k.slope * q;
    if (q >= 1.f) return k.slope * q + (1.f - k.slope);
    return k.half_over_sig1 * tanhf(k.half_c * q - k.quarter_c) + 0.5f;
}

__device__ __forceinline__ float mitchell(float xv) {
    float ax = fabsf(xv);
    if (ax >= 2.f) return 0.f;
    float ax2 = ax * ax, ax3 = ax2 * ax;
    if (ax < 1.f) return 7.f / 6.f * ax3 - 2.f * ax2 + 8.f / 9.f;
    return -7.f / 18.f * ax3 + 2.f * ax2 - 10.f / 3.f * ax + 16.f / 9.f;
}

__device__ __forceinline__ float robidoux(float r2, const KC k) {
    if (r2 >= 4.f) return 0.f;
    float r = sqrtf(r2 + 1e-8f);
    if (r2 < 1.f) return r2 * (-3.f * r + k.a2) + k.a0;
    float t = r - 2.f;
    return (r + k.m_in_root) * t * t;
}

// Pack [p0,s0,p1,s1,p2,s2] per pixel (linear read, linear write).
__global__ __launch_bounds__(256)
void pack_kernel(const float* __restrict__ img, float* __restrict__ packed, KC k) {
    int i = blockIdx.x * 256 + threadIdx.x;
    if (i >= HW_IN / 2) return;
    int x2 = i * 2;
    float2 c0 = *(const float2*)&img[x2];
    float2 c1 = *(const float2*)&img[HW_IN + x2];
    float2 c2 = *(const float2*)&img[2 * HW_IN + x2];
    float4 o0 = make_float4(c0.x, inv_sigmoid(c0.x, k), c1.x, inv_sigmoid(c1.x, k));
    float4 o1 = make_float4(c2.x, inv_sigmoid(c2.x, k), c0.y, inv_sigmoid(c0.y, k));
    float4 o2 = make_float4(c1.y, inv_sigmoid(c1.y, k), c2.y, inv_sigmoid(c2.y, k));
    float4* o = (float4*)packed + (size_t)3 * i;
    o[0] = o0; o[1] = o1; o[2] = o2;
}

__global__ __launch_bounds__(256)   // NO min-waves bound: round 4 proved it spills
void lohalo_lds(const float* __restrict__ packed, const float* __restrict__ grid,
                float* __restrict__ out, KC k) {
    __shared__ float sm[SROWS * RS];   // 18816 B
    __shared__ int sred[16];

    // XCD-aware swizzle: 2304 blocks, 288 contiguous per XCD (6 block-rows)
    const int bid = blockIdx.x;
    const int swz = (bid & 7) * 288 + (bid >> 3);
    const int bx = swz % 48, by = swz / 48;

    const int tid = threadIdx.x;
    const int lx = tid & 15, ly = tid >> 4;
    const int x = bx * 16 + lx;
    const int y = by * 16 + ly;
    const int pix = y * W_OUT + x;

    // ---- Jacobian ----
    const float2* G = (const float2*)grid;
    float2 gc  = G[pix];
    float2 gxm = G[y * W_OUT + max(x - 1, 0)];
    float2 gxp = G[y * W_OUT + min(x + 1, W_OUT - 1)];
    float2 gym = G[max(y - 1, 0) * W_OUT + x];
    float2 gyp = G[min(y + 1, H_OUT - 1) * W_OUT + x];
    float J00 = (gxp.x - gxm.x) * 0.5f, J10 = (gxp.y - gxm.y) * 0.5f;
    float J01 = (gyp.x - gym.x) * 0.5f, J11 = (gyp.y - gym.y) * 0.5f;
    float det = J00 * J11 - J01 * J10 + 1e-8f;
    float idet = 1.f / det;
    float a  = J11 * idet, b = -J01 * idet;
    float cI = -J10 * idet, d = J00 * idet;
    float n11 = a * a + b * b, n12 = a * cI + b * d, n22 = cI * cI + d * d;
    float frob = n11 + n22;
    float disc = frob * frob - 4.f * idet * idet;
    float sdisc = sqrtf(fmaxf(disc, 0.f));
    float twice = frob + sdisc;
    float s1s1 = 0.5f * twice, s2s2 = 0.5f * (frob - sdisc);
    float major = sqrtf(fmaxf(s1s1, 1.f));
    float minr  = sqrtf(fmaxf(s2s2, 1.f));
    float rmaj = 1.f / major, rmin = 1.f / minr;
    float diff1 = s1s1 - n11, diff2 = s1s1 - n22;
    bool  cnd  = diff1 * diff1 >= diff2 * diff2;
    float tu11 = cnd ? n12 : diff2;
    float tu21 = cnd ? diff1 : n12;
    float nrm = sqrtf(tu11 * tu11 + tu21 * tu21);
    float u11 = nrm > 0.f ? tu11 / nrm : 1.f;
    float u21 = nrm > 0.f ? tu21 / nrm : 0.f;
    float cMx = u11 * rmaj, cMy = u21 * rmaj;
    float cmx = -u21 * rmin, cmy = u11 * rmin;
    float theta = rmaj * rmin;
    bool need_ewa = twice > 2.f;

    float fix = floorf(gc.x), fiy = floorf(gc.y);
    int ix = (int)fix, iy = (int)fiy;
    float fx = gc.x - (fix + 0.5f);
    float fy = gc.y - (fiy + 0.5f);

    // ---- block bbox ----
    int mnx = ix, mxx = ix, mny = iy, mxy = iy;
#pragma unroll
    for (int m = 1; m < 64; m <<= 1) {
        mnx = min(mnx, __shfl_xor(mnx, m));
        mxx = max(mxx, __shfl_xor(mxx, m));
        mny = min(mny, __shfl_xor(mny, m));
        mxy = max(mxy, __shfl_xor(mxy, m));
    }
    const int wid = tid >> 6;
    if ((tid & 63) == 0) {
        sred[wid * 4 + 0] = mnx;
        sred[wid * 4 + 1] = mxx;
        sred[wid * 4 + 2] = mny;
        sred[wid * 4 + 3] = mxy;
    }
    __syncthreads();
    mnx = min(min(sred[0], sred[4]),  min(sred[8],  sred[12]));
    mxx = max(max(sred[1], sred[5]),  max(sred[9],  sred[13]));
    mny = min(min(sred[2], sred[6]),  min(sred[10], sred[14]));
    mxy = max(max(sred[3], sred[7]),  max(sred[11], sred[15]));

    const int x0 = (mnx - 2) & ~1;   // even -> float4-aligned packed origin
    const int y0 = mny - 2;
    const bool fits = (mxx + 3 - x0 < SPX) && (mxy + 3 - y0 < SROWS);

    // ---- per-pixel weights (the only persistent arrays) ----
    float my6[6], qya[6], qyb[6], mx6[6], qxa[6], qxb[6];
#pragma unroll
    for (int t = 0; t < 6; t++) {
        float relx = fx - (float)(t - 2);
        float rely = fy - (float)(t - 2);
        mx6[t] = mitchell(relx);
        my6[t] = mitchell(rely);
        qxa[t] = relx * cMx; qxb[t] = relx * cmx;
        qya[t] = rely * cMy; qyb[t] = rely * cmy;
    }

    float ms0 = 0.f, ms1 = 0.f, ms2 = 0.f;
    float es0 = 0.f, es1 = 0.f, es2 = 0.f, tw = 0.f;

    if (fits) {
        // ---- stage clamped tile: tile (r,c) = packed[clamp(y0+r), clamp(x0+c)]
        if (x0 >= 0 && x0 + SPX <= W_IN) {
            for (int j = tid; j < NELEM4; j += 256) {
                int r = j / (RS / 4);
                int q = j - r * (RS / 4);
                int gr = min(max(y0 + r, 0), H_IN - 1);
                const float4* src = (const float4*)(packed + ((size_t)gr * W_IN + x0) * 6) + q;
                *(float4*)&sm[r * RS + q * 4] = *src;
            }
        } else {
            for (int j = tid; j < SROWS * SPX; j += 256) {
                int r = j / SPX;
                int c = j - r * SPX;
                int gr = min(max(y0 + r, 0), H_IN - 1);
                int gcc = min(max(x0 + c, 0), W_IN - 1);
                const float2* src = (const float2*)(packed + ((size_t)gr * W_IN + gcc) * 6);
                float2 a0 = src[0], a1 = src[1], a2 = src[2];
                int o = r * RS + c * 6;
                *(float2*)&sm[o]     = a0;
                *(float2*)&sm[o + 2] = a1;
                *(float2*)&sm[o + 4] = a2;
            }
        }
        __syncthreads();

        // ---- tap loop: one base pointer, immediate offsets, clamping already baked in
        const float* sp = &sm[(iy - 2 - y0) * RS + (ix - 2 - x0) * 6];
#pragma unroll
        for (int ty = 0; ty < 6; ty++) {
            const float* rp = sp + ty * RS;
            const float wmy = my6[ty];
            const float qy1 = qya[ty], qy2 = qyb[ty];
#pragma unroll
            for (int tx = 0; tx < 6; tx++) {
                float2 f0 = *(const float2*)(rp + tx * 6);
                float2 f1 = *(const float2*)(rp + tx * 6 + 2);
                float2 f2 = *(const float2*)(rp + tx * 6 + 4);
                float wm = mx6[tx] * wmy;
                ms0 = fmaf(f0.y, wm, ms0);
                ms1 = fmaf(f1.y, wm, ms1);
                ms2 = fmaf(f2.y, wm, ms2);
                float q1 = qxa[tx] + qy1;
                float q2 = qxb[tx] + qy2;
                float r2 = q1 * q1 + q2 * q2;
                float we = robidoux(r2, k);
                tw += we;
                es0 = fmaf(f0.x, we, es0);
                es1 = fmaf(f1.x, we, es1);
                es2 = fmaf(f2.x, we, es2);
            }
        }
    } else {
        // safety net: direct gather from packed with per-tap clamp
#pragma unroll
        for (int ty = 0; ty < 6; ty++) {
            const int gy2 = min(max(iy + (ty - 2), 0), H_IN - 1);
            const int rb = gy2 * W_IN;
            const float wmy = my6[ty];
            const float qy1 = qya[ty], qy2 = qyb[ty];
#pragma unroll
            for (int tx = 0; tx < 6; tx++) {
                const int gx2 = min(max(ix + (tx - 2), 0), W_IN - 1);
                const float* pp = packed + (size_t)(rb + gx2) * 6;
                float2 f0 = *(const float2*)(pp);
                float2 f1 = *(const float2*)(pp + 2);
                float2 f2 = *(const float2*)(pp + 4);
                float wm = mx6[tx] * wmy;
                ms0 = fmaf(f0.y, wm, ms0);
                ms1 = fmaf(f1.y, wm, ms1);
                ms2 = fmaf(f2.y, wm, ms2);
                float q1 = qxa[tx] + qy1;
                float q2 = qxb[tx] + qy2;
                float r2 = q1 * q1 + q2 * q2;
                float we = robidoux(r2, k);
                tw += we;
                es0 = fmaf(f0.x, we, es0);
                es1 = fmaf(f1.x, we, es1);
                es2 = fmaf(f2.x, we, es2);
            }
        }
    }

    tw += 1e-8f;
    float itw = 1.f / tw;
    float mv0 = ext_sigmoid(ms0, k);
    float mv1 = ext_sigmoid(ms1, k);
    float mv2 = ext_sigmoid(ms2, k);
    float om = 1.f - theta;
    out[pix]              = need_ewa ? theta * mv0 + om * (es0 * itw) : mv0;
    out[HW_OUT + pix]     = need_ewa ? theta * mv1 + om * (es1 * itw) : mv1;
    out[2 * HW_OUT + pix] = need_ewa ? theta * mv2 + om * (es2 * itw) : mv2;
}

// Fallback if ws too small: direct gather from img (unpacked).
__global__ __launch_bounds__(256)
void lohalo_fallback(const float* __restrict__ img, const float* __restrict__ grid,
                     float* __restrict__ out, KC k) {
    const int tid = threadIdx.x;
    const int lx = tid & 15, ly = tid >> 4;
    const int x = blockIdx.x * 16 + lx;
    const int y = blockIdx.y * 16 + ly;
    const int pix = y * W_OUT + x;

    const float2* G = (const float2*)grid;
    float2 gc  = G[pix];
    float2 gxm = G[y * W_OUT + max(x - 1, 0)];
    float2 gxp = G[y * W_OUT + min(x + 1, W_OUT - 1)];
    float2 gym = G[max(y - 1, 0) * W_OUT + x];
    float2 gyp = G[min(y + 1, H_OUT - 1) * W_OUT + x];
    float J00 = (gxp.x - gxm.x) * 0.5f, J10 = (gxp.y - gxm.y) * 0.5f;
    float J01 = (gyp.x - gym.x) * 0.5f, J11 = (gyp.y - gym.y) * 0.5f;
    float det = J00 * J11 - J01 * J10 + 1e-8f;
    float idet = 1.f / det;
    float a  = J11 * idet, b = -J01 * idet;
    float cI = -J10 * idet, d = J00 * idet;
    float n11 = a * a + b * b, n12 = a * cI + b * d, n22 = cI * cI + d * d;
    float frob = n11 + n22;
    float disc = frob * frob - 4.f * idet * idet;
    float sdisc = sqrtf(fmaxf(disc, 0.f));
    float twice = frob + sdisc;
    float s1s1 = 0.5f * twice, s2s2 = 0.5f * (frob - sdisc);
    float major = sqrtf(fmaxf(s1s1, 1.f));
    float minr  = sqrtf(fmaxf(s2s2, 1.f));
    float rmaj = 1.f / major, rmin = 1.f / minr;
    float diff1 = s1s1 - n11, diff2 = s1s1 - n22;
    bool  cnd  = diff1 * diff1 >= diff2 * diff2;
    float tu11 = cnd ? n12 : diff2;
    float tu21 = cnd ? diff1 : n12;
    float nrm = sqrtf(tu11 * tu11 + tu21 * tu21);
    float u11 = nrm > 0.f ? tu11 / nrm : 1.f;
    float u21 = nrm > 0.f ? tu21 / nrm : 0.f;
    float cMx = u11 * rmaj, cMy = u21 * rmaj;
    float cmx = -u21 * rmin, cmy = u11 * rmin;
    float theta = rmaj * rmin;
    bool need_ewa = twice > 2.f;

    float fix = floorf(gc.x), fiy = floorf(gc.y);
    int ix = (int)fix, iy = (int)fiy;
    float fx = gc.x - (fix + 0.5f);
    float fy = gc.y - (fiy + 0.5f);

    float mtx[6], mty[6], qxa6[6], qxb6[6], qya6[6], qyb6[6];
    int cxi[6], cyi[6];
#pragma unroll
    for (int t = 0; t < 6; t++) {
        float relx = fx - (float)(t - 2);
        float rely = fy - (float)(t - 2);
        mtx[t] = mitchell(relx);
        mty[t] = mitchell(rely);
        qxa6[t] = relx * cMx; qxb6[t] = relx * cmx;
        qya6[t] = rely * cMy; qyb6[t] = rely * cmy;
        cxi[t] = min(max(ix + (t - 2), 0), W_IN - 1);
        cyi[t] = min(max(iy + (t - 2), 0), H_IN - 1);
    }
    float ms0 = 0.f, ms1 = 0.f, ms2 = 0.f;
    float es0 = 0.f, es1 = 0.f, es2 = 0.f, tw = 0.f;
#pragma unroll
    for (int ty = 0; ty < 6; ty++) {
        const int rb = cyi[ty] * W_IN;
        const float wmy = mty[ty];
#pragma unroll
        for (int tx = 0; tx < 6; tx++) {
            const int off = rb + cxi[tx];
            float p0 = img[off];
            float p1 = img[off + HW_IN];
            float p2 = img[off + 2 * HW_IN];
            float s0 = inv_sigmoid(p0, k);
            float s1 = inv_sigmoid(p1, k);
            float s2 = inv_sigmoid(p2, k);
            float wm = mtx[tx] * wmy;
            ms0 = fmaf(s0, wm, ms0);
            ms1 = fmaf(s1, wm, ms1);
            ms2 = fmaf(s2, wm, ms2);
            float q1 = qxa6[tx] + qya6[ty];
            float q2 = qxb6[tx] + qyb6[ty];
            float r2 = q1 * q1 + q2 * q2;
            float we = robidoux(r2, k);
            tw += we;
            es0 = fmaf(p0, we, es0);
            es1 = fmaf(p1, we, es1);
            es2 = fmaf(p2, we, es2);
        }
    }
    tw += 1e-8f;
    float itw = 1.f / tw;
    float mv0 = ext_sigmoid(ms0, k);
    float mv1 = ext_sigmoid(ms1, k);
    float mv2 = ext_sigmoid(ms2, k);
    float om = 1.f - theta;
    out[pix]              = need_ewa ? theta * mv0 + om * (es0 * itw) : mv0;
    out[HW_OUT + pix]     = need_ewa ? theta * mv1 + om * (es1 * itw) : mv1;
    out[2 * HW_OUT + pix] = need_ewa ? theta * mv2 + om * (es2 * itw) : mv2;
}

extern "C" void kernel_launch(void* const* d_in, const int* in_sizes, int n_in,
                              void* d_out, int out_size, void* d_ws, size_t ws_size,
                              hipStream_t stream) {
    const float* img  = (const float*)d_in[0];
    const float* grid = (const float*)d_in[1];
    float* out = (float*)d_out;

    KC k;
    const double cc = 3.38589;
    const double s1 = tanh(0.25 * cc);
    const double slope = (1.0 / s1 - s1) * 0.25 * cc;
    k.sig1 = (float)s1;
    k.slope = (float)slope;
    k.inv = (float)(1.0 / slope);
    k.two_over_c = (float)(2.0 / cc);
    k.half_c = (float)(0.5 * cc);
    k.quarter_c = (float)(0.25 * cc);
    k.half_over_sig1 = (float)(0.5 / s1);
    const double sq2 = sqrt(2.0);
    k.a2 = (float)((45739.0 + 7164.0 * sq2) / 10319.0);
    k.a0 = (float)((-8926.0 - 14328.0 * sq2) / 10319.0);
    k.m_in_root = (float)((-103.0 - 36.0 * sq2) / (7.0 + 72.0 * sq2));

    const size_t packed_bytes = (size_t)HW_IN * 6 * sizeof(float);   // 24 MB

    if (ws_size >= packed_bytes) {
        float* packed = (float*)d_ws;
        int npairs = HW_IN / 2;
        pack_kernel<<<(npairs + 255) / 256, 256, 0, stream>>>(img, packed, k);
        lohalo_lds<<<(W_OUT / 16) * (H_OUT / 16), 256, 0, stream>>>(packed, grid, out, k);
    } else {
        dim3 grd(W_OUT / 16, H_OUT / 16);
        lohalo_fallback<<<grd, 256, 0, stream>>>(img, grid, out, k);
    }
}

// Round 6
// 56.829 us; speedup vs baseline: 5.4085x; 1.7787x over previous
//
#include <hip/hip_runtime.h>
#include <math.h>

#define H_IN  1024
#define W_IN  1024
#define HW_IN (H_IN * W_IN)
#define H_OUT 768
#define W_OUT 768
#define HW_OUT (H_OUT * W_OUT)

// LDS tile: 28x28 pixels x 6 floats (clamped at stage time)
#define SROWS 28
#define SPX   28
#define RS    (SPX * 6)             // 168 floats/row
#define NELEM4 (SROWS * (RS / 4))   // 1176 float4

struct KC {
    float sig1, inv, slope, two_over_c, half_c, quarter_c, half_over_sig1;
    float a2, a0, m_in_root;
};

__device__ __forceinline__ float inv_sigmoid(float q, const KC k) {
    if (q <= 0.f) return q * k.inv;
    if (q >= 1.f) return q * k.inv + (1.f - k.inv);
    float ssq = 2.f * k.sig1 * q - k.sig1;
    ssq = fminf(fmaxf(ssq, -0.999999f), 0.999999f);
    return k.two_over_c * atanhf(ssq) + 0.5f;
}

__device__ __forceinline__ float ext_sigmoid(float q, const KC k) {
    if (q <= 0.f) return k.slope * q;
    if (q >= 1.f) return k.slope * q + (1.f - k.slope);
    return k.half_over_sig1 * tanhf(k.half_c * q - k.quarter_c) + 0.5f;
}

// Branchless Mitchell: v1 = ax^2*(7/6 ax - 2) + 8/9 ; v2 = ((-7/18 ax + 2)ax - 10/3)ax + 16/9
__device__ __forceinline__ float mitchell_b(float xv) {
    float ax = fabsf(xv);
    float v1 = fmaf(ax * ax, fmaf(7.f / 6.f, ax, -2.f), 8.f / 9.f);
    float v2 = fmaf(fmaf(fmaf(-7.f / 18.f, ax, 2.f), ax, -10.f / 3.f), ax, 16.f / 9.f);
    float v = (ax < 1.f) ? v1 : v2;
    return (ax < 2.f) ? v : 0.f;
}

// Branchless Robidoux
__device__ __forceinline__ float robidoux_b(float r2, const KC k) {
    float r = sqrtf(r2 + 1e-8f);
    float w_in = fmaf(r2, fmaf(-3.f, r, k.a2), k.a0);
    float t = r - 2.f;
    float w_out = (r + k.m_in_root) * (t * t);
    float w = (r2 < 1.f) ? w_in : w_out;
    return (r2 < 4.f) ? w : 0.f;
}

// Pack [p0,s0,p1,s1,p2,s2] per pixel (linear read, linear write).
__global__ __launch_bounds__(256)
void pack_kernel(const float* __restrict__ img, float* __restrict__ packed, KC k) {
    int i = blockIdx.x * 256 + threadIdx.x;
    if (i >= HW_IN / 2) return;
    int x2 = i * 2;
    float2 c0 = *(const float2*)&img[x2];
    float2 c1 = *(const float2*)&img[HW_IN + x2];
    float2 c2 = *(const float2*)&img[2 * HW_IN + x2];
    float4 o0 = make_float4(c0.x, inv_sigmoid(c0.x, k), c1.x, inv_sigmoid(c1.x, k));
    float4 o1 = make_float4(c2.x, inv_sigmoid(c2.x, k), c0.y, inv_sigmoid(c0.y, k));
    float4 o2 = make_float4(c1.y, inv_sigmoid(c1.y, k), c2.y, inv_sigmoid(c2.y, k));
    float4* o = (float4*)packed + (size_t)3 * i;
    o[0] = o0; o[1] = o1; o[2] = o2;
}

__global__ __launch_bounds__(256)
void lohalo_lds(const float* __restrict__ packed, const float* __restrict__ grid,
                float* __restrict__ out, KC k) {
    __shared__ float sm[SROWS * RS];   // 18816 B
    __shared__ int sred[16];

    // XCD-aware swizzle: 2304 blocks, 288 contiguous per XCD (6 block-rows)
    const int bid = blockIdx.x;
    const int swz = (bid & 7) * 288 + (bid >> 3);
    const int bx = swz % 48, by = swz / 48;

    const int tid = threadIdx.x;
    const int lx = tid & 15, ly = tid >> 4;
    const int x = bx * 16 + lx;
    const int y = by * 16 + ly;
    const int pix = y * W_OUT + x;

    // ---- Jacobian ----
    const float2* G = (const float2*)grid;
    float2 gc  = G[pix];
    float2 gxm = G[y * W_OUT + max(x - 1, 0)];
    float2 gxp = G[y * W_OUT + min(x + 1, W_OUT - 1)];
    float2 gym = G[max(y - 1, 0) * W_OUT + x];
    float2 gyp = G[min(y + 1, H_OUT - 1) * W_OUT + x];
    float J00 = (gxp.x - gxm.x) * 0.5f, J10 = (gxp.y - gxm.y) * 0.5f;
    float J01 = (gyp.x - gym.x) * 0.5f, J11 = (gyp.y - gym.y) * 0.5f;
    float det = J00 * J11 - J01 * J10 + 1e-8f;
    float idet = 1.f / det;
    float a  = J11 * idet, b = -J01 * idet;
    float cI = -J10 * idet, d = J00 * idet;
    float n11 = a * a + b * b, n12 = a * cI + b * d, n22 = cI * cI + d * d;
    float frob = n11 + n22;
    float disc = frob * frob - 4.f * idet * idet;
    float sdisc = sqrtf(fmaxf(disc, 0.f));
    float twice = frob + sdisc;
    float s1s1 = 0.5f * twice, s2s2 = 0.5f * (frob - sdisc);
    float major = sqrtf(fmaxf(s1s1, 1.f));
    float minr  = sqrtf(fmaxf(s2s2, 1.f));
    float rmaj = 1.f / major, rmin = 1.f / minr;
    float diff1 = s1s1 - n11, diff2 = s1s1 - n22;
    bool  cnd  = diff1 * diff1 >= diff2 * diff2;
    float tu11 = cnd ? n12 : diff2;
    float tu21 = cnd ? diff1 : n12;
    float nrm = sqrtf(tu11 * tu11 + tu21 * tu21);
    float u11 = nrm > 0.f ? tu11 / nrm : 1.f;
    float u21 = nrm > 0.f ? tu21 / nrm : 0.f;
    float cMx = u11 * rmaj, cMy = u21 * rmaj;
    float cmx = -u21 * rmin, cmy = u11 * rmin;
    float theta = rmaj * rmin;
    bool need_ewa = twice > 2.f;

    float fix = floorf(gc.x), fiy = floorf(gc.y);
    int ix = (int)fix, iy = (int)fiy;
    float fx = gc.x - (fix + 0.5f);
    float fy = gc.y - (fiy + 0.5f);

    // ---- block bbox ----
    int mnx = ix, mxx = ix, mny = iy, mxy = iy;
#pragma unroll
    for (int m = 1; m < 64; m <<= 1) {
        mnx = min(mnx, __shfl_xor(mnx, m));
        mxx = max(mxx, __shfl_xor(mxx, m));
        mny = min(mny, __shfl_xor(mny, m));
        mxy = max(mxy, __shfl_xor(mxy, m));
    }
    const int wid = tid >> 6;
    if ((tid & 63) == 0) {
        sred[wid * 4 + 0] = mnx;
        sred[wid * 4 + 1] = mxx;
        sred[wid * 4 + 2] = mny;
        sred[wid * 4 + 3] = mxy;
    }
    __syncthreads();
    mnx = min(min(sred[0], sred[4]),  min(sred[8],  sred[12]));
    mxx = max(max(sred[1], sred[5]),  max(sred[9],  sred[13]));
    mny = min(min(sred[2], sred[6]),  min(sred[10], sred[14]));
    mxy = max(max(sred[3], sred[7]),  max(sred[11], sred[15]));

    const int x0 = (mnx - 2) & ~1;   // even -> float4-aligned packed origin
    const int y0 = mny - 2;
    const bool fits = (mxx + 3 - x0 < SPX) && (mxy + 3 - y0 < SROWS);

    // ---- x-weights only (y recomputed per row to cut live registers) ----
    float mx6[6], qxa[6], qxb[6];
#pragma unroll
    for (int t = 0; t < 6; t++) {
        float relx = fx - (float)(t - 2);
        mx6[t] = mitchell_b(relx);
        qxa[t] = relx * cMx;
        qxb[t] = relx * cmx;
    }

    float ms0 = 0.f, ms1 = 0.f, ms2 = 0.f;
    float es0 = 0.f, es1 = 0.f, es2 = 0.f, tw = 0.f;
    const bool any_ewa = __any(need_ewa);

    if (fits) {
        // ---- stage clamped tile ----
        if (x0 >= 0 && x0 + SPX <= W_IN) {
            for (int j = tid; j < NELEM4; j += 256) {
                int r = j / (RS / 4);
                int q = j - r * (RS / 4);
                int gr = min(max(y0 + r, 0), H_IN - 1);
                const float4* src = (const float4*)(packed + ((size_t)gr * W_IN + x0) * 6) + q;
                *(float4*)&sm[r * RS + q * 4] = *src;
            }
        } else {
            for (int j = tid; j < SROWS * SPX; j += 256) {
                int r = j / SPX;
                int c = j - r * SPX;
                int gr = min(max(y0 + r, 0), H_IN - 1);
                int gcc = min(max(x0 + c, 0), W_IN - 1);
                const float2* src = (const float2*)(packed + ((size_t)gr * W_IN + gcc) * 6);
                float2 a0 = src[0], a1 = src[1], a2 = src[2];
                int o = r * RS + c * 6;
                *(float2*)&sm[o]     = a0;
                *(float2*)&sm[o + 2] = a1;
                *(float2*)&sm[o + 4] = a2;
            }
        }
        __syncthreads();

        const float* sp = &sm[(iy - 2 - y0) * RS + (ix - 2 - x0) * 6];
        if (any_ewa) {
#pragma unroll
            for (int ty = 0; ty < 6; ty++) {
                float rely = fy - (float)(ty - 2);
                float wmy = mitchell_b(rely);
                float qy1 = rely * cMy, qy2 = rely * cmy;
                const float* rp = sp + ty * RS;
                float rs0 = 0.f, rs1 = 0.f, rs2 = 0.f;
#pragma unroll
                for (int tx = 0; tx < 6; tx++) {
                    float2 f0 = *(const float2*)(rp + tx * 6);
                    float2 f1 = *(const float2*)(rp + tx * 6 + 2);
                    float2 f2 = *(const float2*)(rp + tx * 6 + 4);
                    float mxv = mx6[tx];
                    rs0 = fmaf(f0.y, mxv, rs0);
                    rs1 = fmaf(f1.y, mxv, rs1);
                    rs2 = fmaf(f2.y, mxv, rs2);
                    float q1 = qxa[tx] + qy1;
                    float q2 = qxb[tx] + qy2;
                    float r2 = fmaf(q1, q1, q2 * q2);
                    float we = robidoux_b(r2, k);
                    tw += we;
                    es0 = fmaf(f0.x, we, es0);
                    es1 = fmaf(f1.x, we, es1);
                    es2 = fmaf(f2.x, we, es2);
                }
                ms0 = fmaf(rs0, wmy, ms0);
                ms1 = fmaf(rs1, wmy, ms1);
                ms2 = fmaf(rs2, wmy, ms2);
            }
        } else {
#pragma unroll
            for (int ty = 0; ty < 6; ty++) {
                float rely = fy - (float)(ty - 2);
                float wmy = mitchell_b(rely);
                const float* rp = sp + ty * RS;
                float rs0 = 0.f, rs1 = 0.f, rs2 = 0.f;
#pragma unroll
                for (int tx = 0; tx < 6; tx++) {
                    float mxv = mx6[tx];
                    rs0 = fmaf((rp + tx * 6)[1], mxv, rs0);
                    rs1 = fmaf((rp + tx * 6)[3], mxv, rs1);
                    rs2 = fmaf((rp + tx * 6)[5], mxv, rs2);
                }
                ms0 = fmaf(rs0, wmy, ms0);
                ms1 = fmaf(rs1, wmy, ms1);
                ms2 = fmaf(rs2, wmy, ms2);
            }
        }
    } else {
        // safety net: direct gather from packed with per-tap clamp
#pragma unroll
        for (int ty = 0; ty < 6; ty++) {
            float rely = fy - (float)(ty - 2);
            float wmy = mitchell_b(rely);
            float qy1 = rely * cMy, qy2 = rely * cmy;
            const int gy2 = min(max(iy + (ty - 2), 0), H_IN - 1);
            const int rb = gy2 * W_IN;
            float rs0 = 0.f, rs1 = 0.f, rs2 = 0.f;
#pragma unroll
            for (int tx = 0; tx < 6; tx++) {
                const int gx2 = min(max(ix + (tx - 2), 0), W_IN - 1);
                const float* pp = packed + (size_t)(rb + gx2) * 6;
                float2 f0 = *(const float2*)(pp);
                float2 f1 = *(const float2*)(pp + 2);
                float2 f2 = *(const float2*)(pp + 4);
                float mxv = mx6[tx];
                rs0 = fmaf(f0.y, mxv, rs0);
                rs1 = fmaf(f1.y, mxv, rs1);
                rs2 = fmaf(f2.y, mxv, rs2);
                float q1 = qxa[tx] + qy1;
                float q2 = qxb[tx] + qy2;
                float r2 = fmaf(q1, q1, q2 * q2);
                float we = robidoux_b(r2, k);
                tw += we;
                es0 = fmaf(f0.x, we, es0);
                es1 = fmaf(f1.x, we, es1);
                es2 = fmaf(f2.x, we, es2);
            }
            ms0 = fmaf(rs0, wmy, ms0);
            ms1 = fmaf(rs1, wmy, ms1);
            ms2 = fmaf(rs2, wmy, ms2);
        }
    }

    tw += 1e-8f;
    float itw = 1.f / tw;
    float mv0 = ext_sigmoid(ms0, k);
    float mv1 = ext_sigmoid(ms1, k);
    float mv2 = ext_sigmoid(ms2, k);
    float om = 1.f - theta;
    out[pix]              = need_ewa ? theta * mv0 + om * (es0 * itw) : mv0;
    out[HW_OUT + pix]     = need_ewa ? theta * mv1 + om * (es1 * itw) : mv1;
    out[2 * HW_OUT + pix] = need_ewa ? theta * mv2 + om * (es2 * itw) : mv2;
}

// Fallback if ws too small: direct gather from img (unpacked).
__global__ __launch_bounds__(256)
void lohalo_fallback(const float* __restrict__ img, const float* __restrict__ grid,
                     float* __restrict__ out, KC k) {
    const int tid = threadIdx.x;
    const int lx = tid & 15, ly = tid >> 4;
    const int x = blockIdx.x * 16 + lx;
    const int y = blockIdx.y * 16 + ly;
    const int pix = y * W_OUT + x;

    const float2* G = (const float2*)grid;
    float2 gc  = G[pix];
    float2 gxm = G[y * W_OUT + max(x - 1, 0)];
    float2 gxp = G[y * W_OUT + min(x + 1, W_OUT - 1)];
    float2 gym = G[max(y - 1, 0) * W_OUT + x];
    float2 gyp = G[min(y + 1, H_OUT - 1) * W_OUT + x];
    float J00 = (gxp.x - gxm.x) * 0.5f, J10 = (gxp.y - gxm.y) * 0.5f;
    float J01 = (gyp.x - gym.x) * 0.5f, J11 = (gyp.y - gym.y) * 0.5f;
    float det = J00 * J11 - J01 * J10 + 1e-8f;
    float idet = 1.f / det;
    float a  = J11 * idet, b = -J01 * idet;
    float cI = -J10 * idet, d = J00 * idet;
    float n11 = a * a + b * b, n12 = a * cI + b * d, n22 = cI * cI + d * d;
    float frob = n11 + n22;
    float disc = frob * frob - 4.f * idet * idet;
    float sdisc = sqrtf(fmaxf(disc, 0.f));
    float twice = frob + sdisc;
    float s1s1 = 0.5f * twice, s2s2 = 0.5f * (frob - sdisc);
    float major = sqrtf(fmaxf(s1s1, 1.f));
    float minr  = sqrtf(fmaxf(s2s2, 1.f));
    float rmaj = 1.f / major, rmin = 1.f / minr;
    float diff1 = s1s1 - n11, diff2 = s1s1 - n22;
    bool  cnd  = diff1 * diff1 >= diff2 * diff2;
    float tu11 = cnd ? n12 : diff2;
    float tu21 = cnd ? diff1 : n12;
    float nrm = sqrtf(tu11 * tu11 + tu21 * tu21);
    float u11 = nrm > 0.f ? tu11 / nrm : 1.f;
    float u21 = nrm > 0.f ? tu21 / nrm : 0.f;
    float cMx = u11 * rmaj, cMy = u21 * rmaj;
    float cmx = -u21 * rmin, cmy = u11 * rmin;
    float theta = rmaj * rmin;
    bool need_ewa = twice > 2.f;

    float fix = floorf(gc.x), fiy = floorf(gc.y);
    int ix = (int)fix, iy = (int)fiy;
    float fx = gc.x - (fix + 0.5f);
    float fy = gc.y - (fiy + 0.5f);

    float mx6[6], qxa[6], qxb[6];
#pragma unroll
    for (int t = 0; t < 6; t++) {
        float relx = fx - (float)(t - 2);
        mx6[t] = mitchell_b(relx);
        qxa[t] = relx * cMx;
        qxb[t] = relx * cmx;
    }
    float ms0 = 0.f, ms1 = 0.f, ms2 = 0.f;
    float es0 = 0.f, es1 = 0.f, es2 = 0.f, tw = 0.f;
#pragma unroll
    for (int ty = 0; ty < 6; ty++) {
        float rely = fy - (float)(ty - 2);
        float wmy = mitchell_b(rely);
        float qy1 = rely * cMy, qy2 = rely * cmy;
        const int gy2 = min(max(iy + (ty - 2), 0), H_IN - 1);
        const int rb = gy2 * W_IN;
        float rs0 = 0.f, rs1 = 0.f, rs2 = 0.f;
#pragma unroll
        for (int tx = 0; tx < 6; tx++) {
            const int off = rb + min(max(ix + (tx - 2), 0), W_IN - 1);
            float p0 = img[off];
            float p1 = img[off + HW_IN];
            float p2 = img[off + 2 * HW_IN];
            float s0 = inv_sigmoid(p0, k);
            float s1 = inv_sigmoid(p1, k);
            float s2 = inv_sigmoid(p2, k);
            float mxv = mx6[tx];
            rs0 = fmaf(s0, mxv, rs0);
            rs1 = fmaf(s1, mxv, rs1);
            rs2 = fmaf(s2, mxv, rs2);
            float q1 = qxa[tx] + qy1;
            float q2 = qxb[tx] + qy2;
            float r2 = fmaf(q1, q1, q2 * q2);
            float we = robidoux_b(r2, k);
            tw += we;
            es0 = fmaf(p0, we, es0);
            es1 = fmaf(p1, we, es1);
            es2 = fmaf(p2, we, es2);
        }
        ms0 = fmaf(rs0, wmy, ms0);
        ms1 = fmaf(rs1, wmy, ms1);
        ms2 = fmaf(rs2, wmy, ms2);
    }
    tw += 1e-8f;
    float itw = 1.f / tw;
    float mv0 = ext_sigmoid(ms0, k);
    float mv1 = ext_sigmoid(ms1, k);
    float mv2 = ext_sigmoid(ms2, k);
    float om = 1.f - theta;
    out[pix]              = need_ewa ? theta * mv0 + om * (es0 * itw) : mv0;
    out[HW_OUT + pix]     = need_ewa ? theta * mv1 + om * (es1 * itw) : mv1;
    out[2 * HW_OUT + pix] = need_ewa ? theta * mv2 + om * (es2 * itw) : mv2;
}

extern "C" void kernel_launch(void* const* d_in, const int* in_sizes, int n_in,
                              void* d_out, int out_size, void* d_ws, size_t ws_size,
                              hipStream_t stream) {
    const float* img  = (const float*)d_in[0];
    const float* grid = (const float*)d_in[1];
    float* out = (float*)d_out;

    KC k;
    const double cc = 3.38589;
    const double s1 = tanh(0.25 * cc);
    const double slope = (1.0 / s1 - s1) * 0.25 * cc;
    k.sig1 = (float)s1;
    k.slope = (float)slope;
    k.inv = (float)(1.0 / slope);
    k.two_over_c = (float)(2.0 / cc);
    k.half_c = (float)(0.5 * cc);
    k.quarter_c = (float)(0.25 * cc);
    k.half_over_sig1 = (float)(0.5 / s1);
    const double sq2 = sqrt(2.0);
    k.a2 = (float)((45739.0 + 7164.0 * sq2) / 10319.0);
    k.a0 = (float)((-8926.0 - 14328.0 * sq2) / 10319.0);
    k.m_in_root = (float)((-103.0 - 36.0 * sq2) / (7.0 + 72.0 * sq2));

    const size_t packed_bytes = (size_t)HW_IN * 6 * sizeof(float);   // 24 MB

    if (ws_size >= packed_bytes) {
        float* packed = (float*)d_ws;
        int npairs = HW_IN / 2;
        pack_kernel<<<(npairs + 255) / 256, 256, 0, stream>>>(img, packed, k);
        lohalo_lds<<<(W_OUT / 16) * (H_OUT / 16), 256, 0, stream>>>(packed, grid, out, k);
    } else {
        dim3 grd(W_OUT / 16, H_OUT / 16);
        lohalo_fallback<<<grd, 256, 0, stream>>>(img, grid, out, k);
    }
}

// Round 7
// 51.068 us; speedup vs baseline: 6.0187x; 1.1128x over previous
//
#include <hip/hip_runtime.h>
#include <math.h>

#define H_IN  1024
#define W_IN  1024
#define HW_IN (H_IN * W_IN)
#define H_OUT 768
#define W_OUT 768
#define HW_OUT (H_OUT * W_OUT)

// LDS tile: 28x28 pixels x 6 floats (clamped at stage time)
#define SROWS 28
#define SPX   28
#define RS    (SPX * 6)             // 168 floats/row
#define NELEM4 (SROWS * (RS / 4))   // 1176 float4

struct KC {
    float sig1, inv, slope, two_over_c, half_c, quarter_c, half_over_sig1;
    float a2, a0, m_in_root;
};

__device__ __forceinline__ float inv_sigmoid(float q, const KC k) {
    if (q <= 0.f) return q * k.inv;
    if (q >= 1.f) return q * k.inv + (1.f - k.inv);
    float ssq = 2.f * k.sig1 * q - k.sig1;
    ssq = fminf(fmaxf(ssq, -0.999999f), 0.999999f);
    return k.two_over_c * atanhf(ssq) + 0.5f;
}

__device__ __forceinline__ float ext_sigmoid(float q, const KC k) {
    if (q <= 0.f) return k.slope * q;
    if (q >= 1.f) return k.slope * q + (1.f - k.slope);
    return k.half_over_sig1 * tanhf(k.half_c * q - k.quarter_c) + 0.5f;
}

// Branchless Mitchell
__device__ __forceinline__ float mitchell_b(float xv) {
    float ax = fabsf(xv);
    float v1 = fmaf(ax * ax, fmaf(7.f / 6.f, ax, -2.f), 8.f / 9.f);
    float v2 = fmaf(fmaf(fmaf(-7.f / 18.f, ax, 2.f), ax, -10.f / 3.f), ax, 16.f / 9.f);
    float v = (ax < 1.f) ? v1 : v2;
    return (ax < 2.f) ? v : 0.f;
}

// Branchless Robidoux
__device__ __forceinline__ float robidoux_b(float r2, const KC k) {
    float r = sqrtf(r2 + 1e-8f);
    float w_in = fmaf(r2, fmaf(-3.f, r, k.a2), k.a0);
    float t = r - 2.f;
    float w_out = (r + k.m_in_root) * (t * t);
    float w = (r2 < 1.f) ? w_in : w_out;
    return (r2 < 4.f) ? w : 0.f;
}

// Pack [p0,s0,p1,s1,p2,s2] per pixel.
__global__ __launch_bounds__(256)
void pack_kernel(const float* __restrict__ img, float* __restrict__ packed, KC k) {
    int i = blockIdx.x * 256 + threadIdx.x;
    if (i >= HW_IN / 2) return;
    int x2 = i * 2;
    float2 c0 = *(const float2*)&img[x2];
    float2 c1 = *(const float2*)&img[HW_IN + x2];
    float2 c2 = *(const float2*)&img[2 * HW_IN + x2];
    float4 o0 = make_float4(c0.x, inv_sigmoid(c0.x, k), c1.x, inv_sigmoid(c1.x, k));
    float4 o1 = make_float4(c2.x, inv_sigmoid(c2.x, k), c0.y, inv_sigmoid(c0.y, k));
    float4 o2 = make_float4(c1.y, inv_sigmoid(c1.y, k), c2.y, inv_sigmoid(c2.y, k));
    float4* o = (float4*)packed + (size_t)3 * i;
    o[0] = o0; o[1] = o1; o[2] = o2;
}

__global__ __launch_bounds__(256, 3)   // VGPR cap 170 (mild); R4 proved 128 spills
void lohalo_lds(const float* __restrict__ packed, const float* __restrict__ grid,
                float* __restrict__ out, KC k) {
    __shared__ float sm[SROWS * RS];   // 18816 B
    __shared__ int sred[16];

    // XCD-aware swizzle: 2304 blocks, 288 contiguous per XCD
    const int bid = blockIdx.x;
    const int swz = (bid & 7) * 288 + (bid >> 3);
    const int bx = swz % 48, by = swz / 48;

    const int tid = threadIdx.x;
    const int lx = tid & 15, ly = tid >> 4;
    const int x = bx * 16 + lx;
    const int y = by * 16 + ly;
    const int pix = y * W_OUT + x;

    // ---- Jacobian ----
    const float2* G = (const float2*)grid;
    float2 gc  = G[pix];
    float2 gxm = G[y * W_OUT + max(x - 1, 0)];
    float2 gxp = G[y * W_OUT + min(x + 1, W_OUT - 1)];
    float2 gym = G[max(y - 1, 0) * W_OUT + x];
    float2 gyp = G[min(y + 1, H_OUT - 1) * W_OUT + x];
    float J00 = (gxp.x - gxm.x) * 0.5f, J10 = (gxp.y - gxm.y) * 0.5f;
    float J01 = (gyp.x - gym.x) * 0.5f, J11 = (gyp.y - gym.y) * 0.5f;
    float det = J00 * J11 - J01 * J10 + 1e-8f;
    float idet = 1.f / det;
    float a  = J11 * idet, b = -J01 * idet;
    float cI = -J10 * idet, d = J00 * idet;
    float n11 = a * a + b * b, n12 = a * cI + b * d, n22 = cI * cI + d * d;
    float frob = n11 + n22;
    float disc = frob * frob - 4.f * idet * idet;
    float sdisc = sqrtf(fmaxf(disc, 0.f));
    float twice = frob + sdisc;
    float s1s1 = 0.5f * twice, s2s2 = 0.5f * (frob - sdisc);
    float major = sqrtf(fmaxf(s1s1, 1.f));
    float minr  = sqrtf(fmaxf(s2s2, 1.f));
    float rmaj = 1.f / major, rmin = 1.f / minr;
    float diff1 = s1s1 - n11, diff2 = s1s1 - n22;
    bool  cnd  = diff1 * diff1 >= diff2 * diff2;
    float tu11 = cnd ? n12 : diff2;
    float tu21 = cnd ? diff1 : n12;
    float nrm = sqrtf(tu11 * tu11 + tu21 * tu21);
    float u11 = nrm > 0.f ? tu11 / nrm : 1.f;
    float u21 = nrm > 0.f ? tu21 / nrm : 0.f;
    float cMx = u11 * rmaj, cMy = u21 * rmaj;
    float cmx = -u21 * rmin, cmy = u11 * rmin;
    float theta = rmaj * rmin;
    bool need_ewa = twice > 2.f;

    float fix = floorf(gc.x), fiy = floorf(gc.y);
    int ix = (int)fix, iy = (int)fiy;
    float fx = gc.x - (fix + 0.5f);
    float fy = gc.y - (fiy + 0.5f);

    // ---- block bbox ----
    int mnx = ix, mxx = ix, mny = iy, mxy = iy;
#pragma unroll
    for (int m = 1; m < 64; m <<= 1) {
        mnx = min(mnx, __shfl_xor(mnx, m));
        mxx = max(mxx, __shfl_xor(mxx, m));
        mny = min(mny, __shfl_xor(mny, m));
        mxy = max(mxy, __shfl_xor(mxy, m));
    }
    const int wid = tid >> 6;
    if ((tid & 63) == 0) {
        sred[wid * 4 + 0] = mnx;
        sred[wid * 4 + 1] = mxx;
        sred[wid * 4 + 2] = mny;
        sred[wid * 4 + 3] = mxy;
    }
    __syncthreads();
    mnx = min(min(sred[0], sred[4]),  min(sred[8],  sred[12]));
    mxx = max(max(sred[1], sred[5]),  max(sred[9],  sred[13]));
    mny = min(min(sred[2], sred[6]),  min(sred[10], sred[14]));
    mxy = max(max(sred[3], sred[7]),  max(sred[11], sred[15]));

    const int x0 = (mnx - 2) & ~1;
    const int y0 = mny - 2;
    const bool fits = (mxx + 3 - x0 < SPX) && (mxy + 3 - y0 < SROWS);

    // ---- Mitchell x-weights: tap 5 (o=+3) is exactly 0, keep 5 ----
    float mx5[5];
#pragma unroll
    for (int t = 0; t < 5; t++) mx5[t] = mitchell_b(fx - (float)(t - 2));
    const float fxp2 = fx + 2.f;

    float ms0 = 0.f, ms1 = 0.f, ms2 = 0.f;
    float es0 = 0.f, es1 = 0.f, es2 = 0.f, tw = 0.f;
    const bool any_ewa = __any(need_ewa);

    if (fits) {
        // ---- stage clamped tile ----
        if (x0 >= 0 && x0 + SPX <= W_IN) {
            for (int j = tid; j < NELEM4; j += 256) {
                int r = j / (RS / 4);
                int q = j - r * (RS / 4);
                int gr = min(max(y0 + r, 0), H_IN - 1);
                const float4* src = (const float4*)(packed + ((size_t)gr * W_IN + x0) * 6) + q;
                *(float4*)&sm[r * RS + q * 4] = *src;
            }
        } else {
            for (int j = tid; j < SROWS * SPX; j += 256) {
                int r = j / SPX;
                int c = j - r * SPX;
                int gr = min(max(y0 + r, 0), H_IN - 1);
                int gcc = min(max(x0 + c, 0), W_IN - 1);
                const float2* src = (const float2*)(packed + ((size_t)gr * W_IN + gcc) * 6);
                float2 a0 = src[0], a1 = src[1], a2 = src[2];
                int o = r * RS + c * 6;
                *(float2*)&sm[o]     = a0;
                *(float2*)&sm[o + 2] = a1;
                *(float2*)&sm[o + 4] = a2;
            }
        }
        __syncthreads();

        const float* sp = &sm[(iy - 2 - y0) * RS + (ix - 2 - x0) * 6];
        if (any_ewa) {
#pragma unroll
            for (int ty = 0; ty < 6; ty++) {
                float rely = fy - (float)(ty - 2);
                float wmy = mitchell_b(rely);
                float q1 = fmaf(fxp2, cMx, rely * cMy);   // tap tx=0
                float q2 = fmaf(fxp2, cmx, rely * cmy);
                const float* rp = sp + ty * RS;
                float rs0 = 0.f, rs1 = 0.f, rs2 = 0.f;
#pragma unroll
                for (int tx = 0; tx < 6; tx++) {
                    float2 f0 = *(const float2*)(rp + tx * 6);
                    float2 f1 = *(const float2*)(rp + tx * 6 + 2);
                    float2 f2 = *(const float2*)(rp + tx * 6 + 4);
                    if (tx < 5) {
                        float mxv = mx5[tx];
                        rs0 = fmaf(f0.y, mxv, rs0);
                        rs1 = fmaf(f1.y, mxv, rs1);
                        rs2 = fmaf(f2.y, mxv, rs2);
                    }
                    float r2 = fmaf(q1, q1, q2 * q2);
                    float we = robidoux_b(r2, k);
                    tw += we;
                    es0 = fmaf(f0.x, we, es0);
                    es1 = fmaf(f1.x, we, es1);
                    es2 = fmaf(f2.x, we, es2);
                    q1 -= cMx;
                    q2 -= cmx;
                }
                if (ty < 5) {
                    ms0 = fmaf(rs0, wmy, ms0);
                    ms1 = fmaf(rs1, wmy, ms1);
                    ms2 = fmaf(rs2, wmy, ms2);
                }
            }
        } else {
#pragma unroll
            for (int ty = 0; ty < 5; ty++) {
                float rely = fy - (float)(ty - 2);
                float wmy = mitchell_b(rely);
                const float* rp = sp + ty * RS;
                float rs0 = 0.f, rs1 = 0.f, rs2 = 0.f;
#pragma unroll
                for (int tx = 0; tx < 5; tx++) {
                    float mxv = mx5[tx];
                    rs0 = fmaf((rp + tx * 6)[1], mxv, rs0);
                    rs1 = fmaf((rp + tx * 6)[3], mxv, rs1);
                    rs2 = fmaf((rp + tx * 6)[5], mxv, rs2);
                }
                ms0 = fmaf(rs0, wmy, ms0);
                ms1 = fmaf(rs1, wmy, ms1);
                ms2 = fmaf(rs2, wmy, ms2);
            }
        }
    } else {
        // safety net: direct gather from packed with per-tap clamp
#pragma unroll
        for (int ty = 0; ty < 6; ty++) {
            float rely = fy - (float)(ty - 2);
            float wmy = mitchell_b(rely);
            float q1 = fmaf(fxp2, cMx, rely * cMy);
            float q2 = fmaf(fxp2, cmx, rely * cmy);
            const int gy2 = min(max(iy + (ty - 2), 0), H_IN - 1);
            const int rb = gy2 * W_IN;
            float rs0 = 0.f, rs1 = 0.f, rs2 = 0.f;
#pragma unroll
            for (int tx = 0; tx < 6; tx++) {
                const int gx2 = min(max(ix + (tx - 2), 0), W_IN - 1);
                const float* pp = packed + (size_t)(rb + gx2) * 6;
                float2 f0 = *(const float2*)(pp);
                float2 f1 = *(const float2*)(pp + 2);
                float2 f2 = *(const float2*)(pp + 4);
                if (tx < 5) {
                    float mxv = mx5[tx];
                    rs0 = fmaf(f0.y, mxv, rs0);
                    rs1 = fmaf(f1.y, mxv, rs1);
                    rs2 = fmaf(f2.y, mxv, rs2);
                }
                float r2 = fmaf(q1, q1, q2 * q2);
                float we = robidoux_b(r2, k);
                tw += we;
                es0 = fmaf(f0.x, we, es0);
                es1 = fmaf(f1.x, we, es1);
                es2 = fmaf(f2.x, we, es2);
                q1 -= cMx;
                q2 -= cmx;
            }
            if (ty < 5) {
                ms0 = fmaf(rs0, wmy, ms0);
                ms1 = fmaf(rs1, wmy, ms1);
                ms2 = fmaf(rs2, wmy, ms2);
            }
        }
    }

    tw += 1e-8f;
    float itw = 1.f / tw;
    float mv0 = ext_sigmoid(ms0, k);
    float mv1 = ext_sigmoid(ms1, k);
    float mv2 = ext_sigmoid(ms2, k);
    float om = 1.f - theta;
    out[pix]              = need_ewa ? theta * mv0 + om * (es0 * itw) : mv0;
    out[HW_OUT + pix]     = need_ewa ? theta * mv1 + om * (es1 * itw) : mv1;
    out[2 * HW_OUT + pix] = need_ewa ? theta * mv2 + om * (es2 * itw) : mv2;
}

// Fallback if ws too small: direct gather from img (unpacked).
__global__ __launch_bounds__(256)
void lohalo_fallback(const float* __restrict__ img, const float* __restrict__ grid,
                     float* __restrict__ out, KC k) {
    const int tid = threadIdx.x;
    const int lx = tid & 15, ly = tid >> 4;
    const int x = blockIdx.x * 16 + lx;
    const int y = blockIdx.y * 16 + ly;
    const int pix = y * W_OUT + x;

    const float2* G = (const float2*)grid;
    float2 gc  = G[pix];
    float2 gxm = G[y * W_OUT + max(x - 1, 0)];
    float2 gxp = G[y * W_OUT + min(x + 1, W_OUT - 1)];
    float2 gym = G[max(y - 1, 0) * W_OUT + x];
    float2 gyp = G[min(y + 1, H_OUT - 1) * W_OUT + x];
    float J00 = (gxp.x - gxm.x) * 0.5f, J10 = (gxp.y - gxm.y) * 0.5f;
    float J01 = (gyp.x - gym.x) * 0.5f, J11 = (gyp.y - gym.y) * 0.5f;
    float det = J00 * J11 - J01 * J10 + 1e-8f;
    float idet = 1.f / det;
    float a  = J11 * idet, b = -J01 * idet;
    float cI = -J10 * idet, d = J00 * idet;
    float n11 = a * a + b * b, n12 = a * cI + b * d, n22 = cI * cI + d * d;
    float frob = n11 + n22;
    float disc = frob * frob - 4.f * idet * idet;
    float sdisc = sqrtf(fmaxf(disc, 0.f));
    float twice = frob + sdisc;
    float s1s1 = 0.5f * twice, s2s2 = 0.5f * (frob - sdisc);
    float major = sqrtf(fmaxf(s1s1, 1.f));
    float minr  = sqrtf(fmaxf(s2s2, 1.f));
    float rmaj = 1.f / major, rmin = 1.f / minr;
    float diff1 = s1s1 - n11, diff2 = s1s1 - n22;
    bool  cnd  = diff1 * diff1 >= diff2 * diff2;
    float tu11 = cnd ? n12 : diff2;
    float tu21 = cnd ? diff1 : n12;
    float nrm = sqrtf(tu11 * tu11 + tu21 * tu21);
    float u11 = nrm > 0.f ? tu11 / nrm : 1.f;
    float u21 = nrm > 0.f ? tu21 / nrm : 0.f;
    float cMx = u11 * rmaj, cMy = u21 * rmaj;
    float cmx = -u21 * rmin, cmy = u11 * rmin;
    float theta = rmaj * rmin;
    bool need_ewa = twice > 2.f;

    float fix = floorf(gc.x), fiy = floorf(gc.y);
    int ix = (int)fix, iy = (int)fiy;
    float fx = gc.x - (fix + 0.5f);
    float fy = gc.y - (fiy + 0.5f);

    float mx5[5];
#pragma unroll
    for (int t = 0; t < 5; t++) mx5[t] = mitchell_b(fx - (float)(t - 2));
    const float fxp2 = fx + 2.f;

    float ms0 = 0.f, ms1 = 0.f, ms2 = 0.f;
    float es0 = 0.f, es1 = 0.f, es2 = 0.f, tw = 0.f;
#pragma unroll
    for (int ty = 0; ty < 6; ty++) {
        float rely = fy - (float)(ty - 2);
        float wmy = mitchell_b(rely);
        float q1 = fmaf(fxp2, cMx, rely * cMy);
        float q2 = fmaf(fxp2, cmx, rely * cmy);
        const int gy2 = min(max(iy + (ty - 2), 0), H_IN - 1);
        const int rb = gy2 * W_IN;
        float rs0 = 0.f, rs1 = 0.f, rs2 = 0.f;
#pragma unroll
        for (int tx = 0; tx < 6; tx++) {
            const int off = rb + min(max(ix + (tx - 2), 0), W_IN - 1);
            float p0 = img[off];
            float p1 = img[off + HW_IN];
            float p2 = img[off + 2 * HW_IN];
            if (tx < 5) {
                float s0 = inv_sigmoid(p0, k);
                float s1 = inv_sigmoid(p1, k);
                float s2 = inv_sigmoid(p2, k);
                float mxv = mx5[tx];
                rs0 = fmaf(s0, mxv, rs0);
                rs1 = fmaf(s1, mxv, rs1);
                rs2 = fmaf(s2, mxv, rs2);
            }
            float r2 = fmaf(q1, q1, q2 * q2);
            float we = robidoux_b(r2, k);
            tw += we;
            es0 = fmaf(p0, we, es0);
            es1 = fmaf(p1, we, es1);
            es2 = fmaf(p2, we, es2);
            q1 -= cMx;
            q2 -= cmx;
        }
        if (ty < 5) {
            ms0 = fmaf(rs0, wmy, ms0);
            ms1 = fmaf(rs1, wmy, ms1);
            ms2 = fmaf(rs2, wmy, ms2);
        }
    }
    tw += 1e-8f;
    float itw = 1.f / tw;
    float mv0 = ext_sigmoid(ms0, k);
    float mv1 = ext_sigmoid(ms1, k);
    float mv2 = ext_sigmoid(ms2, k);
    float om = 1.f - theta;
    out[pix]              = need_ewa ? theta * mv0 + om * (es0 * itw) : mv0;
    out[HW_OUT + pix]     = need_ewa ? theta * mv1 + om * (es1 * itw) : mv1;
    out[2 * HW_OUT + pix] = need_ewa ? theta * mv2 + om * (es2 * itw) : mv2;
}

extern "C" void kernel_launch(void* const* d_in, const int* in_sizes, int n_in,
                              void* d_out, int out_size, void* d_ws, size_t ws_size,
                              hipStream_t stream) {
    const float* img  = (const float*)d_in[0];
    const float* grid = (const float*)d_in[1];
    float* out = (float*)d_out;

    KC k;
    const double cc = 3.38589;
    const double s1 = tanh(0.25 * cc);
    const double slope = (1.0 / s1 - s1) * 0.25 * cc;
    k.sig1 = (float)s1;
    k.slope = (float)slope;
    k.inv = (float)(1.0 / slope);
    k.two_over_c = (float)(2.0 / cc);
    k.half_c = (float)(0.5 * cc);
    k.quarter_c = (float)(0.25 * cc);
    k.half_over_sig1 = (float)(0.5 / s1);
    const double sq2 = sqrt(2.0);
    k.a2 = (float)((45739.0 + 7164.0 * sq2) / 10319.0);
    k.a0 = (float)((-8926.0 - 14328.0 * sq2) / 10319.0);
    k.m_in_root = (float)((-103.0 - 36.0 * sq2) / (7.0 + 72.0 * sq2));

    const size_t packed_bytes = (size_t)HW_IN * 6 * sizeof(float);   // 24 MB

    if (ws_size >= packed_bytes) {
        float* packed = (float*)d_ws;
        int npairs = HW_IN / 2;
        pack_kernel<<<(npairs + 255) / 256, 256, 0, stream>>>(img, packed, k);
        lohalo_lds<<<(W_OUT / 16) * (H_OUT / 16), 256, 0, stream>>>(packed, grid, out, k);
    } else {
        dim3 grd(W_OUT / 16, H_OUT / 16);
        lohalo_fallback<<<grd, 256, 0, stream>>>(img, grid, out, k);
    }
}

// Round 8
// 49.159 us; speedup vs baseline: 6.2524x; 1.0388x over previous
//
#include <hip/hip_runtime.h>
#include <math.h>

#define H_IN  1024
#define W_IN  1024
#define HW_IN (H_IN * W_IN)
#define H_OUT 768
#define W_OUT 768
#define HW_OUT (H_OUT * W_OUT)

// LDS tile: 28 rows x 32 px, interleaved [p,s] per channel, clamped at stage time
#define SROWS 28
#define SPX   32
#define RS    (SPX * 6 + 8)        // 200 floats/row; %32 = 8 bank stagger
#define NLD4  (3 * SROWS * (SPX / 4))   // 672 float4 staging loads

struct KC {
    float sig1, inv, slope, two_over_c, half_c, quarter_c, half_over_sig1;
    float a2, a0, m_in_root;
};

__device__ __forceinline__ float inv_sigmoid(float q, const KC k) {
    if (q <= 0.f) return q * k.inv;
    if (q >= 1.f) return q * k.inv + (1.f - k.inv);
    float ssq = 2.f * k.sig1 * q - k.sig1;
    ssq = fminf(fmaxf(ssq, -0.999999f), 0.999999f);
    return k.two_over_c * atanhf(ssq) + 0.5f;
}

__device__ __forceinline__ float ext_sigmoid(float q, const KC k) {
    if (q <= 0.f) return k.slope * q;
    if (q >= 1.f) return k.slope * q + (1.f - k.slope);
    return k.half_over_sig1 * tanhf(k.half_c * q - k.quarter_c) + 0.5f;
}

// Branchless Mitchell
__device__ __forceinline__ float mitchell_b(float xv) {
    float ax = fabsf(xv);
    float v1 = fmaf(ax * ax, fmaf(7.f / 6.f, ax, -2.f), 8.f / 9.f);
    float v2 = fmaf(fmaf(fmaf(-7.f / 18.f, ax, 2.f), ax, -10.f / 3.f), ax, 16.f / 9.f);
    float v = (ax < 1.f) ? v1 : v2;
    return (ax < 2.f) ? v : 0.f;
}

// Branchless Robidoux
__device__ __forceinline__ float robidoux_b(float r2, const KC k) {
    float r = sqrtf(r2 + 1e-8f);
    float w_in = fmaf(r2, fmaf(-3.f, r, k.a2), k.a0);
    float t = r - 2.f;
    float w_out = (r + k.m_in_root) * (t * t);
    float w = (r2 < 1.f) ? w_in : w_out;
    return (r2 < 4.f) ? w : 0.f;
}

__global__ __launch_bounds__(256, 3)   // VGPR cap ~170 (mild); 128 spills (R4)
void lohalo_fused(const float* __restrict__ img, const float* __restrict__ grid,
                  float* __restrict__ out, KC k) {
    __shared__ float sm[SROWS * RS];   // 22400 B
    __shared__ int sred[16];

    // XCD-aware swizzle: 2304 blocks, 288 contiguous per XCD
    const int bid = blockIdx.x;
    const int swz = (bid & 7) * 288 + (bid >> 3);
    const int bx = swz % 48, by = swz / 48;

    const int tid = threadIdx.x;
    const int lx = tid & 15, ly = tid >> 4;
    const int x = bx * 16 + lx;
    const int y = by * 16 + ly;
    const int pix = y * W_OUT + x;

    // ---- Jacobian ----
    const float2* G = (const float2*)grid;
    float2 gc  = G[pix];
    float2 gxm = G[y * W_OUT + max(x - 1, 0)];
    float2 gxp = G[y * W_OUT + min(x + 1, W_OUT - 1)];
    float2 gym = G[max(y - 1, 0) * W_OUT + x];
    float2 gyp = G[min(y + 1, H_OUT - 1) * W_OUT + x];
    float J00 = (gxp.x - gxm.x) * 0.5f, J10 = (gxp.y - gxm.y) * 0.5f;
    float J01 = (gyp.x - gym.x) * 0.5f, J11 = (gyp.y - gym.y) * 0.5f;
    float det = J00 * J11 - J01 * J10 + 1e-8f;
    float idet = 1.f / det;
    float a  = J11 * idet, b = -J01 * idet;
    float cI = -J10 * idet, d = J00 * idet;
    float n11 = a * a + b * b, n12 = a * cI + b * d, n22 = cI * cI + d * d;
    float frob = n11 + n22;
    float disc = frob * frob - 4.f * idet * idet;
    float sdisc = sqrtf(fmaxf(disc, 0.f));
    float twice = frob + sdisc;
    float s1s1 = 0.5f * twice, s2s2 = 0.5f * (frob - sdisc);
    float major = sqrtf(fmaxf(s1s1, 1.f));
    float minr  = sqrtf(fmaxf(s2s2, 1.f));
    float rmaj = 1.f / major, rmin = 1.f / minr;
    float diff1 = s1s1 - n11, diff2 = s1s1 - n22;
    bool  cnd  = diff1 * diff1 >= diff2 * diff2;
    float tu11 = cnd ? n12 : diff2;
    float tu21 = cnd ? diff1 : n12;
    float nrm = sqrtf(tu11 * tu11 + tu21 * tu21);
    float u11 = nrm > 0.f ? tu11 / nrm : 1.f;
    float u21 = nrm > 0.f ? tu21 / nrm : 0.f;
    float cMx = u11 * rmaj, cMy = u21 * rmaj;
    float cmx = -u21 * rmin, cmy = u11 * rmin;
    float theta = rmaj * rmin;
    bool need_ewa = twice > 2.f;

    float fix = floorf(gc.x), fiy = floorf(gc.y);
    int ix = (int)fix, iy = (int)fiy;
    float fx = gc.x - (fix + 0.5f);
    float fy = gc.y - (fiy + 0.5f);

    // ---- block bbox ----
    int mnx = ix, mxx = ix, mny = iy, mxy = iy;
#pragma unroll
    for (int m = 1; m < 64; m <<= 1) {
        mnx = min(mnx, __shfl_xor(mnx, m));
        mxx = max(mxx, __shfl_xor(mxx, m));
        mny = min(mny, __shfl_xor(mny, m));
        mxy = max(mxy, __shfl_xor(mxy, m));
    }
    const int wid = tid >> 6;
    if ((tid & 63) == 0) {
        sred[wid * 4 + 0] = mnx;
        sred[wid * 4 + 1] = mxx;
        sred[wid * 4 + 2] = mny;
        sred[wid * 4 + 3] = mxy;
    }
    __syncthreads();
    mnx = min(min(sred[0], sred[4]),  min(sred[8],  sred[12]));
    mxx = max(max(sred[1], sred[5]),  max(sred[9],  sred[13]));
    mny = min(min(sred[2], sred[6]),  min(sred[10], sred[14]));
    mxy = max(max(sred[3], sred[7]),  max(sred[11], sred[15]));

    const int x0 = (mnx - 2) & ~3;   // float4-aligned img origin
    const int y0 = mny - 2;
    const bool fits = (mxx + 3 - x0 < SPX) && (mxy + 3 - y0 < SROWS);

    // ---- Mitchell x-weights: tap 5 (o=+3) is exactly 0, keep 5 ----
    float mx5[5];
#pragma unroll
    for (int t = 0; t < 5; t++) mx5[t] = mitchell_b(fx - (float)(t - 2));
    const float fxp2 = fx + 2.f;

    float ms0 = 0.f, ms1 = 0.f, ms2 = 0.f;
    float es0 = 0.f, es1 = 0.f, es2 = 0.f, tw = 0.f;
    const bool any_ewa = __any(need_ewa);

    if (fits) {
        // ---- fused staging: load img, compute sigmoid, write (p,s) pairs ----
        if (x0 >= 0 && x0 + SPX <= W_IN) {
            for (int j = tid; j < NLD4; j += 256) {
                int p   = j / (SROWS * (SPX / 4));
                int rem = j - p * (SROWS * (SPX / 4));
                int r   = rem >> 3;
                int q   = rem & 7;
                int gr  = min(max(y0 + r, 0), H_IN - 1);
                float4 v = *(const float4*)&img[(size_t)p * HW_IN + (size_t)gr * W_IN + x0 + q * 4];
                float* o = &sm[r * RS + (q * 4) * 6 + p * 2];
                *(float2*)(o)      = make_float2(v.x, inv_sigmoid(v.x, k));
                *(float2*)(o + 6)  = make_float2(v.y, inv_sigmoid(v.y, k));
                *(float2*)(o + 12) = make_float2(v.z, inv_sigmoid(v.z, k));
                *(float2*)(o + 18) = make_float2(v.w, inv_sigmoid(v.w, k));
            }
        } else {
            for (int j = tid; j < SROWS * SPX; j += 256) {
                int r = j / SPX;
                int c = j - r * SPX;
                int gr  = min(max(y0 + r, 0), H_IN - 1);
                int gcc = min(max(x0 + c, 0), W_IN - 1);
                const float* base = &img[(size_t)gr * W_IN + gcc];
                int o = r * RS + c * 6;
#pragma unroll
                for (int p = 0; p < 3; p++) {
                    float pv = base[(size_t)p * HW_IN];
                    *(float2*)&sm[o + p * 2] = make_float2(pv, inv_sigmoid(pv, k));
                }
            }
        }
        __syncthreads();

        const float* sp = &sm[(iy - 2 - y0) * RS + (ix - 2 - x0) * 6];
        if (any_ewa) {
#pragma unroll
            for (int ty = 0; ty < 6; ty++) {
                float rely = fy - (float)(ty - 2);
                float wmy = mitchell_b(rely);
                float q1 = fmaf(fxp2, cMx, rely * cMy);   // tap tx=0
                float q2 = fmaf(fxp2, cmx, rely * cmy);
                const float* rp = sp + ty * RS;
                float rs0 = 0.f, rs1 = 0.f, rs2 = 0.f;
#pragma unroll
                for (int tx = 0; tx < 6; tx++) {
                    float2 f0 = *(const float2*)(rp + tx * 6);
                    float2 f1 = *(const float2*)(rp + tx * 6 + 2);
                    float2 f2 = *(const float2*)(rp + tx * 6 + 4);
                    if (tx < 5) {
                        float mxv = mx5[tx];
                        rs0 = fmaf(f0.y, mxv, rs0);
                        rs1 = fmaf(f1.y, mxv, rs1);
                        rs2 = fmaf(f2.y, mxv, rs2);
                    }
                    float r2 = fmaf(q1, q1, q2 * q2);
                    float we = robidoux_b(r2, k);
                    tw += we;
                    es0 = fmaf(f0.x, we, es0);
                    es1 = fmaf(f1.x, we, es1);
                    es2 = fmaf(f2.x, we, es2);
                    q1 -= cMx;
                    q2 -= cmx;
                }
                if (ty < 5) {
                    ms0 = fmaf(rs0, wmy, ms0);
                    ms1 = fmaf(rs1, wmy, ms1);
                    ms2 = fmaf(rs2, wmy, ms2);
                }
            }
        } else {
#pragma unroll
            for (int ty = 0; ty < 5; ty++) {
                float rely = fy - (float)(ty - 2);
                float wmy = mitchell_b(rely);
                const float* rp = sp + ty * RS;
                float rs0 = 0.f, rs1 = 0.f, rs2 = 0.f;
#pragma unroll
                for (int tx = 0; tx < 5; tx++) {
                    float mxv = mx5[tx];
                    rs0 = fmaf((rp + tx * 6)[1], mxv, rs0);
                    rs1 = fmaf((rp + tx * 6)[3], mxv, rs1);
                    rs2 = fmaf((rp + tx * 6)[5], mxv, rs2);
                }
                ms0 = fmaf(rs0, wmy, ms0);
                ms1 = fmaf(rs1, wmy, ms1);
                ms2 = fmaf(rs2, wmy, ms2);
            }
        }
    } else {
        // safety net: direct gather from img with per-tap clamp + sigmoid
#pragma unroll
        for (int ty = 0; ty < 6; ty++) {
            float rely = fy - (float)(ty - 2);
            float wmy = mitchell_b(rely);
            float q1 = fmaf(fxp2, cMx, rely * cMy);
            float q2 = fmaf(fxp2, cmx, rely * cmy);
            const int gy2 = min(max(iy + (ty - 2), 0), H_IN - 1);
            const int rb = gy2 * W_IN;
            float rs0 = 0.f, rs1 = 0.f, rs2 = 0.f;
#pragma unroll
            for (int tx = 0; tx < 6; tx++) {
                const int off = rb + min(max(ix + (tx - 2), 0), W_IN - 1);
                float p0 = img[off];
                float p1 = img[off + HW_IN];
                float p2 = img[off + 2 * HW_IN];
                if (tx < 5) {
                    float s0 = inv_sigmoid(p0, k);
                    float s1 = inv_sigmoid(p1, k);
                    float s2 = inv_sigmoid(p2, k);
                    float mxv = mx5[tx];
                    rs0 = fmaf(s0, mxv, rs0);
                    rs1 = fmaf(s1, mxv, rs1);
                    rs2 = fmaf(s2, mxv, rs2);
                }
                float r2 = fmaf(q1, q1, q2 * q2);
                float we = robidoux_b(r2, k);
                tw += we;
                es0 = fmaf(p0, we, es0);
                es1 = fmaf(p1, we, es1);
                es2 = fmaf(p2, we, es2);
                q1 -= cMx;
                q2 -= cmx;
            }
            if (ty < 5) {
                ms0 = fmaf(rs0, wmy, ms0);
                ms1 = fmaf(rs1, wmy, ms1);
                ms2 = fmaf(rs2, wmy, ms2);
            }
        }
    }

    tw += 1e-8f;
    float itw = 1.f / tw;
    float mv0 = ext_sigmoid(ms0, k);
    float mv1 = ext_sigmoid(ms1, k);
    float mv2 = ext_sigmoid(ms2, k);
    float om = 1.f - theta;
    out[pix]              = need_ewa ? theta * mv0 + om * (es0 * itw) : mv0;
    out[HW_OUT + pix]     = need_ewa ? theta * mv1 + om * (es1 * itw) : mv1;
    out[2 * HW_OUT + pix] = need_ewa ? theta * mv2 + om * (es2 * itw) : mv2;
}

extern "C" void kernel_launch(void* const* d_in, const int* in_sizes, int n_in,
                              void* d_out, int out_size, void* d_ws, size_t ws_size,
                              hipStream_t stream) {
    const float* img  = (const float*)d_in[0];
    const float* grid = (const float*)d_in[1];
    float* out = (float*)d_out;

    KC k;
    const double cc = 3.38589;
    const double s1 = tanh(0.25 * cc);
    const double slope = (1.0 / s1 - s1) * 0.25 * cc;
    k.sig1 = (float)s1;
    k.slope = (float)slope;
    k.inv = (float)(1.0 / slope);
    k.two_over_c = (float)(2.0 / cc);
    k.half_c = (float)(0.5 * cc);
    k.quarter_c = (float)(0.25 * cc);
    k.half_over_sig1 = (float)(0.5 / s1);
    const double sq2 = sqrt(2.0);
    k.a2 = (float)((45739.0 + 7164.0 * sq2) / 10319.0);
    k.a0 = (float)((-8926.0 - 14328.0 * sq2) / 10319.0);
    k.m_in_root = (float)((-103.0 - 36.0 * sq2) / (7.0 + 72.0 * sq2));

    lohalo_fused<<<(W_OUT / 16) * (H_OUT / 16), 256, 0, stream>>>(img, grid, out, k);
}

// Round 10
// 27.185 us; speedup vs baseline: 11.3061x; 1.8083x over previous
//
#include <hip/hip_runtime.h>
#include <math.h>

#define H_IN  1024
#define W_IN  1024
#define HW_IN (H_IN * W_IN)
#define H_OUT 768
#define W_OUT 768
#define HW_OUT (H_OUT * W_OUT)

// LDS tile: 28 rows x 32 px, interleaved [p,s] per channel, clamped at stage time
#define SROWS 28
#define SPX   32
#define RS    (SPX * 6 + 8)        // 200 floats/row; %32 = 8 bank stagger
#define NLD4  (3 * SROWS * (SPX / 4))   // 672 float4 staging loads

struct KC {
    float tsig1, msig1, atanh_scale;           // inv_sigmoid
    float slope, one_m_slope, half_over_sig1;  // ext_sigmoid
    float exp_a, exp_b;
    float a2, a0, m_in_root;                   // robidoux
};

__device__ __forceinline__ float fast_rcp(float x)  { return __builtin_amdgcn_rcpf(x); }
__device__ __forceinline__ float fast_log2(float x) { return __builtin_amdgcn_logf(x); }   // v_log_f32 = log2
__device__ __forceinline__ float fast_exp2(float x) { return __builtin_amdgcn_exp2f(x); }  // v_exp_f32 = 2^x
__device__ __forceinline__ float fast_rsq(float x)  { return __builtin_amdgcn_rsqf(x); }

// Branchless inv_sigmoid, valid for q in [0,1) (this input's range).
// ssq = sig1*(2q-1) in [-0.69,0.69] -> no clamp needed; continuous at 0/1.
__device__ __forceinline__ float inv_sigmoid(float q, const KC k) {
    float ssq = fmaf(k.tsig1, q, k.msig1);
    float ratio = (1.f + ssq) * fast_rcp(1.f - ssq);
    return fmaf(fast_log2(ratio), k.atanh_scale, 0.5f);
}

// Branchless ext_sigmoid (q = mitchell sum CAN leave [0,1]; keep selects).
__device__ __forceinline__ float ext_sigmoid(float q, const KC k) {
    float lo = k.slope * q;
    float e  = fast_exp2(fmaf(k.exp_a, q, k.exp_b));
    float th = fmaf(-2.f, fast_rcp(e + 1.f), 1.f);
    float mid = fmaf(k.half_over_sig1, th, 0.5f);
    float v = (q <= 0.f) ? lo : mid;
    return (q >= 1.f) ? (lo + k.one_m_slope) : v;
}

// Branchless Mitchell
__device__ __forceinline__ float mitchell_b(float xv) {
    float ax = fabsf(xv);
    float v1 = fmaf(ax * ax, fmaf(7.f / 6.f, ax, -2.f), 8.f / 9.f);
    float v2 = fmaf(fmaf(fmaf(-7.f / 18.f, ax, 2.f), ax, -10.f / 3.f), ax, 16.f / 9.f);
    float v = (ax < 1.f) ? v1 : v2;
    return (ax < 2.f) ? v : 0.f;
}

// Branchless Robidoux
__device__ __forceinline__ float robidoux_b(float r2, const KC k) {
    float r = sqrtf(r2 + 1e-8f);
    float w_in = fmaf(r2, fmaf(-3.f, r, k.a2), k.a0);
    float t = r - 2.f;
    float w_out = (r + k.m_in_root) * (t * t);
    float w = (r2 < 1.f) ? w_in : w_out;
    return (r2 < 4.f) ? w : 0.f;
}

__global__ __launch_bounds__(256, 3)
void lohalo_fused(const float* __restrict__ img, const float* __restrict__ grid,
                  float* __restrict__ out, KC k) {
    __shared__ float sm[SROWS * RS];   // 22400 B
    __shared__ int sred[16];

    // XCD-aware swizzle: 2304 blocks, 288 contiguous per XCD
    const int bid = blockIdx.x;
    const int swz = (bid & 7) * 288 + (bid >> 3);
    const int bx = swz % 48, by = swz / 48;

    const int tid = threadIdx.x;
    const int lx = tid & 15, ly = tid >> 4;
    const int x = bx * 16 + lx;
    const int y = by * 16 + ly;
    const int pix = y * W_OUT + x;

    // ---- Jacobian ----
    const float2* G = (const float2*)grid;
    float2 gc  = G[pix];
    float2 gxm = G[y * W_OUT + max(x - 1, 0)];
    float2 gxp = G[y * W_OUT + min(x + 1, W_OUT - 1)];
    float2 gym = G[max(y - 1, 0) * W_OUT + x];
    float2 gyp = G[min(y + 1, H_OUT - 1) * W_OUT + x];
    float J00 = (gxp.x - gxm.x) * 0.5f, J10 = (gxp.y - gxm.y) * 0.5f;
    float J01 = (gyp.x - gym.x) * 0.5f, J11 = (gyp.y - gym.y) * 0.5f;
    float det = J00 * J11 - J01 * J10 + 1e-8f;
    float idet = fast_rcp(det);
    float a  = J11 * idet, b = -J01 * idet;
    float cI = -J10 * idet, d = J00 * idet;
    float n11 = a * a + b * b, n12 = a * cI + b * d, n22 = cI * cI + d * d;
    float frob = n11 + n22;
    float disc = frob * frob - 4.f * idet * idet;
    float sdisc = sqrtf(fmaxf(disc, 0.f));
    float twice = frob + sdisc;
    float s1s1 = 0.5f * twice, s2s2 = 0.5f * (frob - sdisc);
    float rmaj = fast_rsq(fmaxf(s1s1, 1.f));
    float rmin = fast_rsq(fmaxf(s2s2, 1.f));
    float diff1 = s1s1 - n11, diff2 = s1s1 - n22;
    bool  cnd  = diff1 * diff1 >= diff2 * diff2;
    float tu11 = cnd ? n12 : diff2;
    float tu21 = cnd ? diff1 : n12;
    float nrm = sqrtf(tu11 * tu11 + tu21 * tu21);
    float inrm = fast_rcp(nrm);
    float u11 = nrm > 0.f ? tu11 * inrm : 1.f;
    float u21 = nrm > 0.f ? tu21 * inrm : 0.f;
    float cMx = u11 * rmaj, cMy = u21 * rmaj;
    float cmx = -u21 * rmin, cmy = u11 * rmin;
    float theta = rmaj * rmin;
    bool need_ewa = twice > 2.f;

    float fix = floorf(gc.x), fiy = floorf(gc.y);
    int ix = (int)fix, iy = (int)fiy;
    float fx = gc.x - (fix + 0.5f);
    float fy = gc.y - (fiy + 0.5f);

    // ---- block bbox ----
    int mnx = ix, mxx = ix, mny = iy, mxy = iy;
#pragma unroll
    for (int m = 1; m < 64; m <<= 1) {
        mnx = min(mnx, __shfl_xor(mnx, m));
        mxx = max(mxx, __shfl_xor(mxx, m));
        mny = min(mny, __shfl_xor(mny, m));
        mxy = max(mxy, __shfl_xor(mxy, m));
    }
    const int wid = tid >> 6;
    if ((tid & 63) == 0) {
        sred[wid * 4 + 0] = mnx;
        sred[wid * 4 + 1] = mxx;
        sred[wid * 4 + 2] = mny;
        sred[wid * 4 + 3] = mxy;
    }
    __syncthreads();
    mnx = min(min(sred[0], sred[4]),  min(sred[8],  sred[12]));
    mxx = max(max(sred[1], sred[5]),  max(sred[9],  sred[13]));
    mny = min(min(sred[2], sred[6]),  min(sred[10], sred[14]));
    mxy = max(max(sred[3], sred[7]),  max(sred[11], sred[15]));

    const int x0 = (mnx - 2) & ~3;   // float4-aligned img origin
    const int y0 = mny - 2;
    const bool fits = (mxx + 3 - x0 < SPX) && (mxy + 3 - y0 < SROWS);

    // ---- Mitchell x-weights: tap 5 (o=+3) is exactly 0, keep 5 ----
    float mx5[5];
#pragma unroll
    for (int t = 0; t < 5; t++) mx5[t] = mitchell_b(fx - (float)(t - 2));
    const float fxp2 = fx + 2.f;

    float ms0 = 0.f, ms1 = 0.f, ms2 = 0.f;
    float es0 = 0.f, es1 = 0.f, es2 = 0.f, tw = 0.f;
    const bool any_ewa = __any(need_ewa);

    if (fits) {
        // ---- fused staging: load img, compute sigmoid, write (p,s) pairs ----
        if (x0 >= 0 && x0 + SPX <= W_IN) {
            for (int j = tid; j < NLD4; j += 256) {
                int p   = j / (SROWS * (SPX / 4));
                int rem = j - p * (SROWS * (SPX / 4));
                int r   = rem >> 3;
                int q   = rem & 7;
                int gr  = min(max(y0 + r, 0), H_IN - 1);
                float4 v = *(const float4*)&img[(size_t)p * HW_IN + (size_t)gr * W_IN + x0 + q * 4];
                float* o = &sm[r * RS + (q * 4) * 6 + p * 2];
                *(float2*)(o)      = make_float2(v.x, inv_sigmoid(v.x, k));
                *(float2*)(o + 6)  = make_float2(v.y, inv_sigmoid(v.y, k));
                *(float2*)(o + 12) = make_float2(v.z, inv_sigmoid(v.z, k));
                *(float2*)(o + 18) = make_float2(v.w, inv_sigmoid(v.w, k));
            }
        } else {
            for (int j = tid; j < SROWS * SPX; j += 256) {
                int r = j / SPX;
                int c = j - r * SPX;
                int gr  = min(max(y0 + r, 0), H_IN - 1);
                int gcc = min(max(x0 + c, 0), W_IN - 1);
                const float* base = &img[(size_t)gr * W_IN + gcc];
                int o = r * RS + c * 6;
#pragma unroll
                for (int p = 0; p < 3; p++) {
                    float pv = base[(size_t)p * HW_IN];
                    *(float2*)&sm[o + p * 2] = make_float2(pv, inv_sigmoid(pv, k));
                }
            }
        }
        __syncthreads();

        const float* sp = &sm[(iy - 2 - y0) * RS + (ix - 2 - x0) * 6];
        if (any_ewa) {
#pragma unroll
            for (int ty = 0; ty < 6; ty++) {
                float rely = fy - (float)(ty - 2);
                float wmy = mitchell_b(rely);
                float q1 = fmaf(fxp2, cMx, rely * cMy);   // tap tx=0
                float q2 = fmaf(fxp2, cmx, rely * cmy);
                const float* rp = sp + ty * RS;
                float rs0 = 0.f, rs1 = 0.f, rs2 = 0.f;
#pragma unroll
                for (int tx = 0; tx < 6; tx++) {
                    float2 f0 = *(const float2*)(rp + tx * 6);
                    float2 f1 = *(const float2*)(rp + tx * 6 + 2);
                    float2 f2 = *(const float2*)(rp + tx * 6 + 4);
                    if (tx < 5) {
                        float mxv = mx5[tx];
                        rs0 = fmaf(f0.y, mxv, rs0);
                        rs1 = fmaf(f1.y, mxv, rs1);
                        rs2 = fmaf(f2.y, mxv, rs2);
                    }
                    float r2 = fmaf(q1, q1, q2 * q2);
                    float we = robidoux_b(r2, k);
                    tw += we;
                    es0 = fmaf(f0.x, we, es0);
                    es1 = fmaf(f1.x, we, es1);
                    es2 = fmaf(f2.x, we, es2);
                    q1 -= cMx;
                    q2 -= cmx;
                }
                if (ty < 5) {
                    ms0 = fmaf(rs0, wmy, ms0);
                    ms1 = fmaf(rs1, wmy, ms1);
                    ms2 = fmaf(rs2, wmy, ms2);
                }
            }
        } else {
#pragma unroll
            for (int ty = 0; ty < 5; ty++) {
                float rely = fy - (float)(ty - 2);
                float wmy = mitchell_b(rely);
                const float* rp = sp + ty * RS;
                float rs0 = 0.f, rs1 = 0.f, rs2 = 0.f;
#pragma unroll
                for (int tx = 0; tx < 5; tx++) {
                    float mxv = mx5[tx];
                    rs0 = fmaf((rp + tx * 6)[1], mxv, rs0);
                    rs1 = fmaf((rp + tx * 6)[3], mxv, rs1);
                    rs2 = fmaf((rp + tx * 6)[5], mxv, rs2);
                }
                ms0 = fmaf(rs0, wmy, ms0);
                ms1 = fmaf(rs1, wmy, ms1);
                ms2 = fmaf(rs2, wmy, ms2);
            }
        }
    } else {
        // safety net: direct gather from img with per-tap clamp + sigmoid
#pragma unroll
        for (int ty = 0; ty < 6; ty++) {
            float rely = fy - (float)(ty - 2);
            float wmy = mitchell_b(rely);
            float q1 = fmaf(fxp2, cMx, rely * cMy);
            float q2 = fmaf(fxp2, cmx, rely * cmy);
            const int gy2 = min(max(iy + (ty - 2), 0), H_IN - 1);
            const int rb = gy2 * W_IN;
            float rs0 = 0.f, rs1 = 0.f, rs2 = 0.f;
#pragma unroll
            for (int tx = 0; tx < 6; tx++) {
                const int off = rb + min(max(ix + (tx - 2), 0), W_IN - 1);
                float p0 = img[off];
                float p1 = img[off + HW_IN];
                float p2 = img[off + 2 * HW_IN];
                if (tx < 5) {
                    float s0 = inv_sigmoid(p0, k);
                    float s1 = inv_sigmoid(p1, k);
                    float s2 = inv_sigmoid(p2, k);
                    float mxv = mx5[tx];
                    rs0 = fmaf(s0, mxv, rs0);
                    rs1 = fmaf(s1, mxv, rs1);
                    rs2 = fmaf(s2, mxv, rs2);
                }
                float r2 = fmaf(q1, q1, q2 * q2);
                float we = robidoux_b(r2, k);
                tw += we;
                es0 = fmaf(p0, we, es0);
                es1 = fmaf(p1, we, es1);
                es2 = fmaf(p2, we, es2);
                q1 -= cMx;
                q2 -= cmx;
            }
            if (ty < 5) {
                ms0 = fmaf(rs0, wmy, ms0);
                ms1 = fmaf(rs1, wmy, ms1);
                ms2 = fmaf(rs2, wmy, ms2);
            }
        }
    }

    tw += 1e-8f;
    float itw = fast_rcp(tw);
    float mv0 = ext_sigmoid(ms0, k);
    float mv1 = ext_sigmoid(ms1, k);
    float mv2 = ext_sigmoid(ms2, k);
    float om = 1.f - theta;
    out[pix]              = need_ewa ? theta * mv0 + om * (es0 * itw) : mv0;
    out[HW_OUT + pix]     = need_ewa ? theta * mv1 + om * (es1 * itw) : mv1;
    out[2 * HW_OUT + pix] = need_ewa ? theta * mv2 + om * (es2 * itw) : mv2;
}

extern "C" void kernel_launch(void* const* d_in, const int* in_sizes, int n_in,
                              void* d_out, int out_size, void* d_ws, size_t ws_size,
                              hipStream_t stream) {
    const float* img  = (const float*)d_in[0];
    const float* grid = (const float*)d_in[1];
    float* out = (float*)d_out;

    KC k;
    const double cc = 3.38589;
    const double s1 = tanh(0.25 * cc);
    const double slope = (1.0 / s1 - s1) * 0.25 * cc;
    const double log2e = 1.4426950408889634074;
    const double ln2   = 0.6931471805599453094;
    k.tsig1 = (float)(2.0 * s1);
    k.msig1 = (float)(-s1);
    k.atanh_scale = (float)(ln2 / cc);            // (2/c)*atanh = (ln2/c)*log2
    k.slope = (float)slope;
    k.one_m_slope = (float)(1.0 - slope);
    k.half_over_sig1 = (float)(0.5 / s1);
    k.exp_a = (float)(cc * log2e);                // 2*log2e*(c/2)
    k.exp_b = (float)(-0.5 * cc * log2e);         // 2*log2e*(-c/4)
    const double sq2 = sqrt(2.0);
    k.a2 = (float)((45739.0 + 7164.0 * sq2) / 10319.0);
    k.a0 = (float)((-8926.0 - 14328.0 * sq2) / 10319.0);
    k.m_in_root = (float)((-103.0 - 36.0 * sq2) / (7.0 + 72.0 * sq2));

    lohalo_fused<<<(W_OUT / 16) * (H_OUT / 16), 256, 0, stream>>>(img, grid, out, k);
}

// Round 11
// 26.713 us; speedup vs baseline: 11.5058x; 1.0177x over previous
//
#include <hip/hip_runtime.h>
#include <math.h>

#define H_IN  1024
#define W_IN  1024
#define HW_IN (H_IN * W_IN)
#define H_OUT 768
#define W_OUT 768
#define HW_OUT (H_OUT * W_OUT)

// LDS tile: 28 rows x 32 px, interleaved [p,s] per channel, clamped at stage time
#define SROWS 28
#define SPX   32
#define RS    (SPX * 6 + 8)        // 200 floats/row; %32 = 8 bank stagger
#define NLD4  (3 * SROWS * (SPX / 4))   // 672 float4 staging loads

typedef float v2f __attribute__((ext_vector_type(2)));

struct KC {
    float tsig1, msig1, atanh_scale;           // inv_sigmoid
    float slope, one_m_slope, half_over_sig1;  // ext_sigmoid
    float exp_a, exp_b;
    float a2, a0, m_in_root;                   // robidoux
};

__device__ __forceinline__ float fast_rcp(float x)  { return __builtin_amdgcn_rcpf(x); }
__device__ __forceinline__ float fast_log2(float x) { return __builtin_amdgcn_logf(x); }   // v_log_f32 = log2
__device__ __forceinline__ float fast_exp2(float x) { return __builtin_amdgcn_exp2f(x); }  // v_exp_f32 = 2^x
__device__ __forceinline__ float fast_rsq(float x)  { return __builtin_amdgcn_rsqf(x); }

// Branchless inv_sigmoid, valid for q in [0,1) (this input's range).
__device__ __forceinline__ float inv_sigmoid(float q, const KC k) {
    float ssq = fmaf(k.tsig1, q, k.msig1);
    float ratio = (1.f + ssq) * fast_rcp(1.f - ssq);
    return fmaf(fast_log2(ratio), k.atanh_scale, 0.5f);
}

// Branchless ext_sigmoid (q = mitchell sum CAN leave [0,1]; keep selects).
__device__ __forceinline__ float ext_sigmoid(float q, const KC k) {
    float lo = k.slope * q;
    float e  = fast_exp2(fmaf(k.exp_a, q, k.exp_b));
    float th = fmaf(-2.f, fast_rcp(e + 1.f), 1.f);
    float mid = fmaf(k.half_over_sig1, th, 0.5f);
    float v = (q <= 0.f) ? lo : mid;
    return (q >= 1.f) ? (lo + k.one_m_slope) : v;
}

// Branchless Mitchell (exact 0 for |x|>=2 -> natural tap masking)
__device__ __forceinline__ float mitchell_b(float xv) {
    float ax = fabsf(xv);
    float v1 = fmaf(ax * ax, fmaf(7.f / 6.f, ax, -2.f), 8.f / 9.f);
    float v2 = fmaf(fmaf(fmaf(-7.f / 18.f, ax, 2.f), ax, -10.f / 3.f), ax, 16.f / 9.f);
    float v = (ax < 1.f) ? v1 : v2;
    return (ax < 2.f) ? v : 0.f;
}

// Branchless Robidoux
__device__ __forceinline__ float robidoux_b(float r2, const KC k) {
    float r = sqrtf(r2 + 1e-8f);
    float w_in = fmaf(r2, fmaf(-3.f, r, k.a2), k.a0);
    float t = r - 2.f;
    float w_out = (r + k.m_in_root) * (t * t);
    float w = (r2 < 1.f) ? w_in : w_out;
    return (r2 < 4.f) ? w : 0.f;
}

__global__ __launch_bounds__(256, 3)
void lohalo_fused(const float* __restrict__ img, const float* __restrict__ grid,
                  float* __restrict__ out, KC k) {
    __shared__ float sm[SROWS * RS];   // 22400 B
    __shared__ int sred[16];

    // XCD-aware swizzle: 2304 blocks, 288 contiguous per XCD
    const int bid = blockIdx.x;
    const int swz = (bid & 7) * 288 + (bid >> 3);
    const int bx = swz % 48, by = swz / 48;

    const int tid = threadIdx.x;
    const int lx = tid & 15, ly = tid >> 4;
    const int x = bx * 16 + lx;
    const int y = by * 16 + ly;
    const int pix = y * W_OUT + x;

    // ---- Jacobian ----
    const float2* G = (const float2*)grid;
    float2 gc  = G[pix];
    float2 gxm = G[y * W_OUT + max(x - 1, 0)];
    float2 gxp = G[y * W_OUT + min(x + 1, W_OUT - 1)];
    float2 gym = G[max(y - 1, 0) * W_OUT + x];
    float2 gyp = G[min(y + 1, H_OUT - 1) * W_OUT + x];
    float J00 = (gxp.x - gxm.x) * 0.5f, J10 = (gxp.y - gxm.y) * 0.5f;
    float J01 = (gyp.x - gym.x) * 0.5f, J11 = (gyp.y - gym.y) * 0.5f;
    float det = J00 * J11 - J01 * J10 + 1e-8f;
    float idet = fast_rcp(det);
    float a  = J11 * idet, b = -J01 * idet;
    float cI = -J10 * idet, d = J00 * idet;
    float n11 = a * a + b * b, n12 = a * cI + b * d, n22 = cI * cI + d * d;
    float frob = n11 + n22;
    float disc = frob * frob - 4.f * idet * idet;
    float sdisc = sqrtf(fmaxf(disc, 0.f));
    float twice = frob + sdisc;
    float s1s1 = 0.5f * twice, s2s2 = 0.5f * (frob - sdisc);
    float rmaj = fast_rsq(fmaxf(s1s1, 1.f));
    float rmin = fast_rsq(fmaxf(s2s2, 1.f));
    float diff1 = s1s1 - n11, diff2 = s1s1 - n22;
    bool  cnd  = diff1 * diff1 >= diff2 * diff2;
    float tu11 = cnd ? n12 : diff2;
    float tu21 = cnd ? diff1 : n12;
    float nrm = sqrtf(tu11 * tu11 + tu21 * tu21);
    float inrm = fast_rcp(nrm);
    float u11 = nrm > 0.f ? tu11 * inrm : 1.f;
    float u21 = nrm > 0.f ? tu21 * inrm : 0.f;
    float cMx = u11 * rmaj, cMy = u21 * rmaj;
    float cmx = -u21 * rmin, cmy = u11 * rmin;
    float theta = rmaj * rmin;
    bool need_ewa = twice > 2.f;

    float fix = floorf(gc.x), fiy = floorf(gc.y);
    int ix = (int)fix, iy = (int)fiy;
    float fx = gc.x - (fix + 0.5f);
    float fy = gc.y - (fiy + 0.5f);

    // ---- block bbox ----
    int mnx = ix, mxx = ix, mny = iy, mxy = iy;
#pragma unroll
    for (int m = 1; m < 64; m <<= 1) {
        mnx = min(mnx, __shfl_xor(mnx, m));
        mxx = max(mxx, __shfl_xor(mxx, m));
        mny = min(mny, __shfl_xor(mny, m));
        mxy = max(mxy, __shfl_xor(mxy, m));
    }
    const int wid = tid >> 6;
    if ((tid & 63) == 0) {
        sred[wid * 4 + 0] = mnx;
        sred[wid * 4 + 1] = mxx;
        sred[wid * 4 + 2] = mny;
        sred[wid * 4 + 3] = mxy;
    }
    __syncthreads();
    mnx = min(min(sred[0], sred[4]),  min(sred[8],  sred[12]));
    mxx = max(max(sred[1], sred[5]),  max(sred[9],  sred[13]));
    mny = min(min(sred[2], sred[6]),  min(sred[10], sred[14]));
    mxy = max(max(sred[3], sred[7]),  max(sred[11], sred[15]));

    const int x0 = (mnx - 2) & ~3;   // float4-aligned img origin
    const int y0 = mny - 2;
    const bool fits = (mxx + 3 - x0 < SPX) && (mxy + 3 - y0 < SROWS);

    // ---- Mitchell x-weights (mx6[5] is naturally exact 0) ----
    float mx6[6];
#pragma unroll
    for (int t = 0; t < 6; t++) mx6[t] = mitchell_b(fx - (float)(t - 2));
    const float fxp2 = fx + 2.f;

    // packed accumulators: .x = EWA(p), .y = Mitchell(s)
    v2f a0 = {0.f, 0.f}, a1 = {0.f, 0.f}, a2acc = {0.f, 0.f};
    float tw = 0.f;
    const bool any_ewa = __any(need_ewa);

    if (fits) {
        // ---- fused staging: load img, compute sigmoid, write (p,s) pairs ----
        if (x0 >= 0 && x0 + SPX <= W_IN) {
            for (int j = tid; j < NLD4; j += 256) {
                int p   = j / (SROWS * (SPX / 4));
                int rem = j - p * (SROWS * (SPX / 4));
                int r   = rem >> 3;
                int q   = rem & 7;
                int gr  = min(max(y0 + r, 0), H_IN - 1);
                float4 v = *(const float4*)&img[(size_t)p * HW_IN + (size_t)gr * W_IN + x0 + q * 4];
                float* o = &sm[r * RS + (q * 4) * 6 + p * 2];
                *(float2*)(o)      = make_float2(v.x, inv_sigmoid(v.x, k));
                *(float2*)(o + 6)  = make_float2(v.y, inv_sigmoid(v.y, k));
                *(float2*)(o + 12) = make_float2(v.z, inv_sigmoid(v.z, k));
                *(float2*)(o + 18) = make_float2(v.w, inv_sigmoid(v.w, k));
            }
        } else {
            for (int j = tid; j < SROWS * SPX; j += 256) {
                int r = j / SPX;
                int c = j - r * SPX;
                int gr  = min(max(y0 + r, 0), H_IN - 1);
                int gcc = min(max(x0 + c, 0), W_IN - 1);
                const float* base = &img[(size_t)gr * W_IN + gcc];
                int o = r * RS + c * 6;
#pragma unroll
                for (int p = 0; p < 3; p++) {
                    float pv = base[(size_t)p * HW_IN];
                    *(float2*)&sm[o + p * 2] = make_float2(pv, inv_sigmoid(pv, k));
                }
            }
        }
        __syncthreads();

        const float* sp = &sm[(iy - 2 - y0) * RS + (ix - 2 - x0) * 6];
        if (any_ewa) {
            const v2f cM = {cMx, cmx};
#pragma unroll
            for (int ty = 0; ty < 6; ty++) {
                float rely = fy - (float)(ty - 2);
                float wmy = mitchell_b(rely);          // exact 0 for ty=5 band
                v2f q = { fmaf(fxp2, cMx, rely * cMy),
                          fmaf(fxp2, cmx, rely * cmy) };
                float mxw[6];
#pragma unroll
                for (int t = 0; t < 6; t++) mxw[t] = mx6[t] * wmy;
                const float* rp = sp + ty * RS;
#pragma unroll
                for (int tx = 0; tx < 6; tx++) {
                    v2f f0 = *(const v2f*)(rp + tx * 6);
                    v2f f1 = *(const v2f*)(rp + tx * 6 + 2);
                    v2f f2 = *(const v2f*)(rp + tx * 6 + 4);
                    float r2 = fmaf(q.x, q.x, q.y * q.y);
                    float we = robidoux_b(r2, k);
                    tw += we;
                    v2f w = { we, mxw[tx] };
                    a0    = __builtin_elementwise_fma(f0, w, a0);
                    a1    = __builtin_elementwise_fma(f1, w, a1);
                    a2acc = __builtin_elementwise_fma(f2, w, a2acc);
                    q = q - cM;
                }
            }
        } else {
#pragma unroll
            for (int ty = 0; ty < 5; ty++) {
                float rely = fy - (float)(ty - 2);
                float wmy = mitchell_b(rely);
                const float* rp = sp + ty * RS;
                float rs0 = 0.f, rs1 = 0.f, rs2 = 0.f;
#pragma unroll
                for (int tx = 0; tx < 5; tx++) {
                    float mxv = mx6[tx];
                    rs0 = fmaf((rp + tx * 6)[1], mxv, rs0);
                    rs1 = fmaf((rp + tx * 6)[3], mxv, rs1);
                    rs2 = fmaf((rp + tx * 6)[5], mxv, rs2);
                }
                a0.y    = fmaf(rs0, wmy, a0.y);
                a1.y    = fmaf(rs1, wmy, a1.y);
                a2acc.y = fmaf(rs2, wmy, a2acc.y);
            }
        }
    } else {
        // safety net: direct gather from img with per-tap clamp + sigmoid
#pragma unroll
        for (int ty = 0; ty < 6; ty++) {
            float rely = fy - (float)(ty - 2);
            float wmy = mitchell_b(rely);
            float q1 = fmaf(fxp2, cMx, rely * cMy);
            float q2 = fmaf(fxp2, cmx, rely * cmy);
            const int gy2 = min(max(iy + (ty - 2), 0), H_IN - 1);
            const int rb = gy2 * W_IN;
#pragma unroll
            for (int tx = 0; tx < 6; tx++) {
                const int off = rb + min(max(ix + (tx - 2), 0), W_IN - 1);
                float p0 = img[off];
                float p1 = img[off + HW_IN];
                float p2 = img[off + 2 * HW_IN];
                float mxw = mx6[tx] * wmy;
                float r2 = fmaf(q1, q1, q2 * q2);
                float we = robidoux_b(r2, k);
                tw += we;
                a0.x    = fmaf(p0, we, a0.x);
                a1.x    = fmaf(p1, we, a1.x);
                a2acc.x = fmaf(p2, we, a2acc.x);
                a0.y    = fmaf(inv_sigmoid(p0, k), mxw, a0.y);
                a1.y    = fmaf(inv_sigmoid(p1, k), mxw, a1.y);
                a2acc.y = fmaf(inv_sigmoid(p2, k), mxw, a2acc.y);
                q1 -= cMx;
                q2 -= cmx;
            }
        }
    }

    tw += 1e-8f;
    float itw = fast_rcp(tw);
    float mv0 = ext_sigmoid(a0.y, k);
    float mv1 = ext_sigmoid(a1.y, k);
    float mv2 = ext_sigmoid(a2acc.y, k);
    float om = 1.f - theta;
    out[pix]              = need_ewa ? theta * mv0 + om * (a0.x * itw)    : mv0;
    out[HW_OUT + pix]     = need_ewa ? theta * mv1 + om * (a1.x * itw)    : mv1;
    out[2 * HW_OUT + pix] = need_ewa ? theta * mv2 + om * (a2acc.x * itw) : mv2;
}

extern "C" void kernel_launch(void* const* d_in, const int* in_sizes, int n_in,
                              void* d_out, int out_size, void* d_ws, size_t ws_size,
                              hipStream_t stream) {
    const float* img  = (const float*)d_in[0];
    const float* grid = (const float*)d_in[1];
    float* out = (float*)d_out;

    KC k;
    const double cc = 3.38589;
    const double s1 = tanh(0.25 * cc);
    const double slope = (1.0 / s1 - s1) * 0.25 * cc;
    const double log2e = 1.4426950408889634074;
    const double ln2   = 0.6931471805599453094;
    k.tsig1 = (float)(2.0 * s1);
    k.msig1 = (float)(-s1);
    k.atanh_scale = (float)(ln2 / cc);            // (2/c)*atanh = (ln2/c)*log2
    k.slope = (float)slope;
    k.one_m_slope = (float)(1.0 - slope);
    k.half_over_sig1 = (float)(0.5 / s1);
    k.exp_a = (float)(cc * log2e);
    k.exp_b = (float)(-0.5 * cc * log2e);
    const double sq2 = sqrt(2.0);
    k.a2 = (float)((45739.0 + 7164.0 * sq2) / 10319.0);
    k.a0 = (float)((-8926.0 - 14328.0 * sq2) / 10319.0);
    k.m_in_root = (float)((-103.0 - 36.0 * sq2) / (7.0 + 72.0 * sq2));

    lohalo_fused<<<(W_OUT / 16) * (H_OUT / 16), 256, 0, stream>>>(img, grid, out, k);
}